// Round 1
// baseline (634.720 us; speedup 1.0000x reference)
//
#include <hip/hip_runtime.h>
#include <hip/hip_bf16.h>
#include <math.h>

#define NB 2
#define NN 512
#define CSD 384
#define CZD 128
#define NH 12
#define NC 16
#define NPQ 4
#define NPV 8
// derived
#define HC 192      // H*C
#define QPDIM 144   // 3*H*PQ
#define KVPDIM 432  // 3*H*(PQ+PV)
#define FEATD 2112  // H*C + H*PV*4 + H*CZ

// ---------------- Kernel 1: projections + to_global ----------------
// grid 256 blocks x 4 rows, 256 threads
__global__ __launch_bounds__(256) void k_proj(
    const float* __restrict__ single, const float* __restrict__ rot, const float* __restrict__ trans,
    const float* __restrict__ wq, const float* __restrict__ bq,
    const float* __restrict__ wkv, const float* __restrict__ bkv,
    const float* __restrict__ wqp, const float* __restrict__ bqp,
    const float* __restrict__ wkvp, const float* __restrict__ bkvp,
    float* __restrict__ qws, float* __restrict__ kws, float* __restrict__ vws,
    float* __restrict__ qgws, float* __restrict__ kgws, float* __restrict__ vgws)
{
    __shared__ float s_single[4][CSD];
    __shared__ float s_qp[4][QPDIM];
    __shared__ float s_kvp[4][KVPDIM];
    const int t = threadIdx.x;
    const int row0 = blockIdx.x * 4;

    for (int idx = t; idx < 4 * CSD; idx += 256) {
        int r = idx / CSD, k = idx % CSD;
        s_single[r][k] = single[(size_t)(row0 + r) * CSD + k];
    }
    __syncthreads();

    for (int o = t; o < 1152; o += 256) {
        const float* wrow;
        if (o < 192)      wrow = wq   + (size_t)o * CSD;
        else if (o < 576) wrow = wkv  + (size_t)(o - 192) * CSD;
        else if (o < 720) wrow = wqp  + (size_t)(o - 576) * CSD;
        else              wrow = wkvp + (size_t)(o - 720) * CSD;
        float acc[4] = {0.f, 0.f, 0.f, 0.f};
        for (int k = 0; k < CSD; k += 4) {
            float4 w4 = *(const float4*)(wrow + k);
            #pragma unroll
            for (int r = 0; r < 4; r++) {
                float4 s4 = *(const float4*)(&s_single[r][k]);
                acc[r] += w4.x * s4.x + w4.y * s4.y + w4.z * s4.z + w4.w * s4.w;
            }
        }
        if (o < 192) {
            float bv = bq[o];
            #pragma unroll
            for (int r = 0; r < 4; r++) qws[(size_t)(row0 + r) * HC + o] = acc[r] + bv;
        } else if (o < 576) {
            int f = o - 192; float bv = bkv[f];
            int h = f >> 5, cc = f & 31;
            if (cc < 16) {
                #pragma unroll
                for (int r = 0; r < 4; r++) kws[(size_t)(row0 + r) * HC + h * 16 + cc] = acc[r] + bv;
            } else {
                #pragma unroll
                for (int r = 0; r < 4; r++) vws[(size_t)(row0 + r) * HC + h * 16 + cc - 16] = acc[r] + bv;
            }
        } else if (o < 720) {
            int f = o - 576; float bv = bqp[f];
            #pragma unroll
            for (int r = 0; r < 4; r++) s_qp[r][f] = acc[r] + bv;
        } else {
            int f = o - 720; float bv = bkvp[f];
            #pragma unroll
            for (int r = 0; r < 4; r++) s_kvp[r][f] = acc[r] + bv;
        }
    }
    __syncthreads();

    // point transforms: 4 rows * (48 qg + 48 kg + 96 vg) = 768 tasks
    for (int id = t; id < 768; id += 256) {
        int r = id / 192, rem = id % 192;
        int grow = row0 + r;
        const float* R = rot + (size_t)grow * 9;
        const float* T = trans + (size_t)grow * 3;
        float lx, ly, lz; float* dst;
        if (rem < 48) {
            lx = s_qp[r][rem]; ly = s_qp[r][48 + rem]; lz = s_qp[r][96 + rem];
            dst = qgws + ((size_t)grow * 48 + rem) * 3;
        } else if (rem < 96) {
            int idx = rem - 48; int h = idx >> 2, p = idx & 3;
            int fb = h * 12 + p;
            lx = s_kvp[r][fb]; ly = s_kvp[r][144 + fb]; lz = s_kvp[r][288 + fb];
            dst = kgws + ((size_t)grow * 48 + idx) * 3;
        } else {
            int idx = rem - 96; int h = idx >> 3, p = idx & 7;
            int fb = h * 12 + 4 + p;
            lx = s_kvp[r][fb]; ly = s_kvp[r][144 + fb]; lz = s_kvp[r][288 + fb];
            dst = vgws + ((size_t)grow * 96 + idx) * 3;
        }
        dst[0] = R[0] * lx + R[1] * ly + R[2] * lz + T[0];
        dst[1] = R[3] * lx + R[4] * ly + R[5] * lz + T[1];
        dst[2] = R[6] * lx + R[7] * ly + R[8] * lz + T[2];
    }
}

// ---------------- Kernel 2: bias = pair @ wb.T + bb ----------------
// 32 rows/block, 8 threads/row (coalesced 512B per row)
__global__ __launch_bounds__(256) void k_bias(
    const float* __restrict__ pair, const float* __restrict__ wb, const float* __restrict__ bb,
    float* __restrict__ biasws)
{
    __shared__ float wbs[NH * CZD];
    int t = threadIdx.x;
    for (int i = t; i < NH * CZD; i += 256) wbs[i] = wb[i];
    __syncthreads();
    int rib = t >> 3, sub = t & 7;
    size_t grow = (size_t)blockIdx.x * 32 + rib; // < B*N*N
    const float* prow = pair + grow * CZD + sub * 16;
    float acc[NH];
    #pragma unroll
    for (int h = 0; h < NH; h++) acc[h] = 0.f;
    #pragma unroll
    for (int g = 0; g < 4; g++) {
        float4 p4 = *(const float4*)(prow + g * 4);
        float pv[4] = {p4.x, p4.y, p4.z, p4.w};
        #pragma unroll
        for (int e = 0; e < 4; e++) {
            int d = sub * 16 + g * 4 + e;
            #pragma unroll
            for (int h = 0; h < NH; h++) acc[h] += pv[e] * wbs[h * CZD + d];
        }
    }
    #pragma unroll
    for (int off = 1; off < 8; off <<= 1) {
        #pragma unroll
        for (int h = 0; h < NH; h++) acc[h] += __shfl_xor(acc[h], off, 64);
    }
    if (sub == 0) {
        #pragma unroll
        for (int h = 0; h < NH; h++) biasws[grow * NH + h] = acc[h] + bb[h];
    }
}

// ---------------- Kernel 3: fused attention per (b,i) ----------------
__global__ __launch_bounds__(256) void k_attn(
    const float* __restrict__ pair, const float* __restrict__ rot, const float* __restrict__ trans,
    const float* __restrict__ hw,
    const float* __restrict__ qws, const float* __restrict__ kws, const float* __restrict__ vws,
    const float* __restrict__ qgws, const float* __restrict__ kgws, const float* __restrict__ vgws,
    const float* __restrict__ biasws, float* __restrict__ feats)
{
    __shared__ float attn_s[NH][NN];
    __shared__ float q_s[HC];
    __shared__ float qg_s[QPDIM];
    __shared__ float coef_s[NH];
    __shared__ float rot_s[9], trans_s[3];
    __shared__ float rp_s[NH][24];

    int t = threadIdx.x;
    int row_i = blockIdx.x;         // b*N + i
    int b = row_i >> 9;
    size_t bbase = (size_t)b * NN;  // first flat row of batch b

    if (t < HC)  q_s[t] = qws[(size_t)row_i * HC + t];
    if (t < QPDIM) qg_s[t] = qgws[(size_t)row_i * QPDIM + t];
    if (t >= 192 && t < 204) {
        int h = t - 192; float x = hw[h];
        // -0.5 * sqrt(1/54) * softplus(hw)
        coef_s[h] = -0.5f * 0.13608276348795434f * log1pf(expf(x));
    }
    if (t >= 204 && t < 213) rot_s[t - 204] = rot[(size_t)row_i * 9 + (t - 204)];
    if (t >= 213 && t < 216) trans_s[t - 213] = trans[(size_t)row_i * 3 + (t - 213)];
    __syncthreads();

    const float rs3C = 0.14433756729740643f; // sqrt(1/48)
    const float rs3  = 0.5773502691896258f;  // sqrt(1/3)

    // logits: 12*512 tasks
    #pragma unroll 1
    for (int kk = 0; kk < 24; kk++) {
        int idx = kk * 256 + t;
        int h = idx >> 9, j = idx & 511;
        const float* krow = kws + (bbase + j) * HC + h * 16;
        float qk = 0.f;
        #pragma unroll
        for (int c4 = 0; c4 < 4; c4++) {
            float4 k4 = *(const float4*)(krow + c4 * 4);
            const float* qr = &q_s[h * 16 + c4 * 4];
            qk += k4.x * qr[0] + k4.y * qr[1] + k4.z * qr[2] + k4.w * qr[3];
        }
        const float* kgrow = kgws + (bbase + j) * QPDIM + h * 12;
        const float* qgr = &qg_s[h * 12];
        float d2 = 0.f;
        #pragma unroll
        for (int e = 0; e < 12; e++) { float dd = qgr[e] - kgrow[e]; d2 += dd * dd; }
        float bv = biasws[((size_t)row_i * NN + j) * NH + h];
        attn_s[h][j] = rs3C * qk + rs3 * bv + coef_s[h] * d2;
    }
    __syncthreads();

    // softmax: wave w handles heads 3w..3w+2
    int w = t >> 6, lane = t & 63;
    for (int hh = 0; hh < 3; hh++) {
        int h = w * 3 + hh;
        float m = -1e30f;
        for (int j = lane; j < NN; j += 64) m = fmaxf(m, attn_s[h][j]);
        #pragma unroll
        for (int off = 32; off >= 1; off >>= 1) m = fmaxf(m, __shfl_xor(m, off, 64));
        float s = 0.f;
        for (int j = lane; j < NN; j += 64) { float e = __expf(attn_s[h][j] - m); attn_s[h][j] = e; s += e; }
        #pragma unroll
        for (int off = 32; off >= 1; off >>= 1) s += __shfl_xor(s, off, 64);
        float inv = 1.0f / s;
        for (int j = lane; j < NN; j += 64) attn_s[h][j] *= inv;
    }
    __syncthreads();

    float* frow = feats + (size_t)row_i * FEATD;

    // out_scalar (192) + rp_g (288)
    for (int id = t; id < 480; id += 256) {
        float acc = 0.f;
        if (id < 192) {
            int h = id >> 4;
            const float* vcol = vws + bbase * HC + id;          // h*16+c == id
            const float* arow = attn_s[h];
            for (int j = 0; j < NN; j++) acc += arow[j] * vcol[(size_t)j * HC];
            frow[id] = acc;
        } else {
            int idx = id - 192;               // 0..287
            int h = idx / 24, rem = idx % 24; // rem = pv*3+o
            const float* vgcol = vgws + bbase * 288 + h * 24 + rem;
            const float* arow = attn_s[h];
            for (int j = 0; j < NN; j++) acc += arow[j] * vgcol[(size_t)j * 288];
            rp_s[h][rem] = acc;
        }
    }

    // out_pair: each thread: d = t&127, 6 heads
    {
        int d = t & 127;
        int hbase = (t >> 7) * 6;
        float acc[6] = {0.f, 0.f, 0.f, 0.f, 0.f, 0.f};
        const float* prow = pair + (size_t)row_i * NN * CZD + d;
        for (int j = 0; j < NN; j++) {
            float pv = prow[(size_t)j * CZD];
            #pragma unroll
            for (int hh = 0; hh < 6; hh++) acc[hh] += attn_s[hbase + hh][j] * pv;
        }
        #pragma unroll
        for (int hh = 0; hh < 6; hh++) frow[576 + (hbase + hh) * CZD + d] = acc[hh];
    }
    __syncthreads();

    // rp_l + norms
    if (t < 96) {
        int h = t >> 3, p = t & 7;
        float d0 = rp_s[h][p * 3 + 0] - trans_s[0];
        float d1 = rp_s[h][p * 3 + 1] - trans_s[1];
        float d2v = rp_s[h][p * 3 + 2] - trans_s[2];
        float l0 = rot_s[0] * d0 + rot_s[3] * d1 + rot_s[6] * d2v;
        float l1 = rot_s[1] * d0 + rot_s[4] * d1 + rot_s[7] * d2v;
        float l2 = rot_s[2] * d0 + rot_s[5] * d1 + rot_s[8] * d2v;
        float nrm = sqrtf(l0 * l0 + l1 * l1 + l2 * l2 + 1e-8f);
        frow[192 + h * 8 + p] = l0;
        frow[288 + h * 8 + p] = l1;
        frow[384 + h * 8 + p] = l2;
        frow[480 + h * 8 + p] = nrm;
    }
}

// ---------------- Kernel 4: out = feats @ wo.T + bo ----------------
__global__ __launch_bounds__(256) void k_out(
    const float* __restrict__ featsws, const float* __restrict__ wo, const float* __restrict__ bo,
    float* __restrict__ out)
{
    __shared__ float fs[4][FEATD];
    int t = threadIdx.x;
    int row0 = blockIdx.x * 4;
    for (int idx = t; idx < 4 * FEATD; idx += 256) {
        int r = idx / FEATD, k = idx % FEATD;
        fs[r][k] = featsws[(size_t)(row0 + r) * FEATD + k];
    }
    __syncthreads();
    for (int o = t; o < CSD; o += 256) {
        const float* wrow = wo + (size_t)o * FEATD;
        float a0 = 0.f, a1 = 0.f, a2 = 0.f, a3 = 0.f;
        for (int k = 0; k < FEATD; k += 4) {
            float4 w4 = *(const float4*)(wrow + k);
            float4 f0 = *(const float4*)(&fs[0][k]);
            float4 f1 = *(const float4*)(&fs[1][k]);
            float4 f2 = *(const float4*)(&fs[2][k]);
            float4 f3 = *(const float4*)(&fs[3][k]);
            a0 += w4.x * f0.x + w4.y * f0.y + w4.z * f0.z + w4.w * f0.w;
            a1 += w4.x * f1.x + w4.y * f1.y + w4.z * f1.z + w4.w * f1.w;
            a2 += w4.x * f2.x + w4.y * f2.y + w4.z * f2.z + w4.w * f2.w;
            a3 += w4.x * f3.x + w4.y * f3.y + w4.z * f3.z + w4.w * f3.w;
        }
        float bv = bo[o];
        out[(size_t)(row0 + 0) * CSD + o] = a0 + bv;
        out[(size_t)(row0 + 1) * CSD + o] = a1 + bv;
        out[(size_t)(row0 + 2) * CSD + o] = a2 + bv;
        out[(size_t)(row0 + 3) * CSD + o] = a3 + bv;
    }
}

extern "C" void kernel_launch(void* const* d_in, const int* in_sizes, int n_in,
                              void* d_out, int out_size, void* d_ws, size_t ws_size,
                              hipStream_t stream) {
    const float* single = (const float*)d_in[0];
    const float* pair   = (const float*)d_in[1];
    const float* rot    = (const float*)d_in[2];
    const float* trans  = (const float*)d_in[3];
    const float* wq     = (const float*)d_in[4];
    const float* bq     = (const float*)d_in[5];
    const float* wkv    = (const float*)d_in[6];
    const float* bkv    = (const float*)d_in[7];
    const float* wqp    = (const float*)d_in[8];
    const float* bqp    = (const float*)d_in[9];
    const float* wkvp   = (const float*)d_in[10];
    const float* bkvp   = (const float*)d_in[11];
    const float* wb     = (const float*)d_in[12];
    const float* bb     = (const float*)d_in[13];
    const float* wo     = (const float*)d_in[14];
    const float* bo     = (const float*)d_in[15];
    const float* hw     = (const float*)d_in[16];
    float* out = (float*)d_out;

    float* ws = (float*)d_ws;
    float* qws    = ws;                 // 2*512*192   = 196608
    float* kws    = qws  + 196608;      // 196608
    float* vws    = kws  + 196608;      // 196608
    float* qgws   = vws  + 196608;      // 2*512*144   = 147456
    float* kgws   = qgws + 147456;      // 147456
    float* vgws   = kgws + 147456;      // 2*512*288   = 294912
    float* biasws = vgws + 294912;      // 2*512*512*12 = 6291456
    float* featsws= biasws + 6291456;   // 2*512*2112  = 2162688
    // total: 9,633,792 floats = 38.5 MB

    hipLaunchKernelGGL(k_proj, dim3(256), dim3(256), 0, stream,
                       single, rot, trans, wq, bq, wkv, bkv, wqp, bqp, wkvp, bkvp,
                       qws, kws, vws, qgws, kgws, vgws);
    hipLaunchKernelGGL(k_bias, dim3(16384), dim3(256), 0, stream, pair, wb, bb, biasws);
    hipLaunchKernelGGL(k_attn, dim3(1024), dim3(256), 0, stream,
                       pair, rot, trans, hw, qws, kws, vws, qgws, kgws, vgws, biasws, featsws);
    hipLaunchKernelGGL(k_out, dim3(256), dim3(256), 0, stream, featsws, wo, bo, out);
}

// Round 2
// 448.065 us; speedup vs baseline: 1.4166x; 1.4166x over previous
//
#include <hip/hip_runtime.h>
#include <hip/hip_bf16.h>
#include <math.h>

#define NB 2
#define NN 512
#define CSD 384
#define CZD 128
#define NH 12
#define NC 16
#define NPQ 4
#define NPV 8
// derived
#define HC 192      // H*C
#define QPDIM 144   // 3*H*PQ
#define KVPDIM 432  // 3*H*(PQ+PV)
#define FEATD 2112  // H*C + H*PV*4 + H*CZ
#define VALLD 512   // padded 480 (192 scalar v + 288 vg)
#define ASTR 516    // attn_s row stride (pad 4: banks 4h+j -> <=2 per bank)

// ---------------- Kernel 1: projections + to_global ----------------
__global__ __launch_bounds__(256) void k_proj(
    const float* __restrict__ single, const float* __restrict__ rot, const float* __restrict__ trans,
    const float* __restrict__ wq, const float* __restrict__ bq,
    const float* __restrict__ wkv, const float* __restrict__ bkv,
    const float* __restrict__ wqp, const float* __restrict__ bqp,
    const float* __restrict__ wkvp, const float* __restrict__ bkvp,
    float* __restrict__ qws, float* __restrict__ kws, float* __restrict__ vall,
    float* __restrict__ qgws, float* __restrict__ kgws)
{
    __shared__ float s_single[4][CSD];
    __shared__ float s_qp[4][QPDIM];
    __shared__ float s_kvp[4][KVPDIM];
    const int t = threadIdx.x;
    const int row0 = blockIdx.x * 4;

    for (int idx = t; idx < 4 * CSD; idx += 256) {
        int r = idx / CSD, k = idx % CSD;
        s_single[r][k] = single[(size_t)(row0 + r) * CSD + k];
    }
    __syncthreads();

    for (int o = t; o < 1152; o += 256) {
        const float* wrow;
        if (o < 192)      wrow = wq   + (size_t)o * CSD;
        else if (o < 576) wrow = wkv  + (size_t)(o - 192) * CSD;
        else if (o < 720) wrow = wqp  + (size_t)(o - 576) * CSD;
        else              wrow = wkvp + (size_t)(o - 720) * CSD;
        float acc[4] = {0.f, 0.f, 0.f, 0.f};
        for (int k = 0; k < CSD; k += 4) {
            float4 w4 = *(const float4*)(wrow + k);
            #pragma unroll
            for (int r = 0; r < 4; r++) {
                float4 s4 = *(const float4*)(&s_single[r][k]);
                acc[r] += w4.x * s4.x + w4.y * s4.y + w4.z * s4.z + w4.w * s4.w;
            }
        }
        if (o < 192) {
            float bv = bq[o];
            #pragma unroll
            for (int r = 0; r < 4; r++) qws[(size_t)(row0 + r) * HC + o] = acc[r] + bv;
        } else if (o < 576) {
            int f = o - 192; float bv = bkv[f];
            int h = f >> 5, cc = f & 31;
            if (cc < 16) {
                #pragma unroll
                for (int r = 0; r < 4; r++) kws[(size_t)(row0 + r) * HC + h * 16 + cc] = acc[r] + bv;
            } else {
                #pragma unroll
                for (int r = 0; r < 4; r++) vall[(size_t)(row0 + r) * VALLD + h * 16 + cc - 16] = acc[r] + bv;
            }
        } else if (o < 720) {
            int f = o - 576; float bv = bqp[f];
            #pragma unroll
            for (int r = 0; r < 4; r++) s_qp[r][f] = acc[r] + bv;
        } else {
            int f = o - 720; float bv = bkvp[f];
            #pragma unroll
            for (int r = 0; r < 4; r++) s_kvp[r][f] = acc[r] + bv;
        }
    }
    __syncthreads();

    // point transforms: 4 rows * (48 qg + 48 kg + 96 vg) = 768 tasks
    for (int id = t; id < 768; id += 256) {
        int r = id / 192, rem = id % 192;
        int grow = row0 + r;
        const float* R = rot + (size_t)grow * 9;
        const float* T = trans + (size_t)grow * 3;
        float lx, ly, lz; float* dst;
        if (rem < 48) {
            lx = s_qp[r][rem]; ly = s_qp[r][48 + rem]; lz = s_qp[r][96 + rem];
            dst = qgws + ((size_t)grow * 48 + rem) * 3;
        } else if (rem < 96) {
            int idx = rem - 48; int h = idx >> 2, p = idx & 3;
            int fb = h * 12 + p;
            lx = s_kvp[r][fb]; ly = s_kvp[r][144 + fb]; lz = s_kvp[r][288 + fb];
            dst = kgws + ((size_t)grow * 48 + idx) * 3;
        } else {
            int idx = rem - 96; int h = idx >> 3, p = idx & 7;
            int fb = h * 12 + 4 + p;
            lx = s_kvp[r][fb]; ly = s_kvp[r][144 + fb]; lz = s_kvp[r][288 + fb];
            dst = vall + (size_t)grow * VALLD + 192 + idx * 3;
        }
        dst[0] = R[0] * lx + R[1] * ly + R[2] * lz + T[0];
        dst[1] = R[3] * lx + R[4] * ly + R[5] * lz + T[1];
        dst[2] = R[6] * lx + R[7] * ly + R[8] * lz + T[2];
    }
}

// ---------------- Kernel 2: fused bias + attention per (b,i) ----------------
__global__ __launch_bounds__(256) void k_attn(
    const float* __restrict__ pair, const float* __restrict__ rot, const float* __restrict__ trans,
    const float* __restrict__ hw, const float* __restrict__ wb, const float* __restrict__ bb,
    const float* __restrict__ qws, const float* __restrict__ kws, const float* __restrict__ vall,
    const float* __restrict__ qgws, const float* __restrict__ kgws,
    float* __restrict__ feats)
{
    __shared__ float attn_s[NH][ASTR];   // 24768 B
    __shared__ float q_s[HC];
    __shared__ float qg_s[QPDIM];
    __shared__ float coef_s[NH];
    __shared__ float rot_s[9], trans_s[3];
    __shared__ float rp2_s[288];
    __shared__ float red_s[480];

    const int t = threadIdx.x;
    const int row_i = blockIdx.x;   // b*N + i
    const int b = row_i >> 9;
    const size_t bbase = (size_t)b * NN;

    if (t < HC)   q_s[t]  = qws[(size_t)row_i * HC + t];
    if (t < QPDIM) qg_s[t] = qgws[(size_t)row_i * QPDIM + t];
    if (t >= 192 && t < 204) {
        int h = t - 192; float x = hw[h];
        coef_s[h] = -0.5f * 0.13608276348795434f * log1pf(expf(x)); // -0.5*sqrt(1/54)*softplus
    }
    if (t >= 204 && t < 213) rot_s[t - 204] = rot[(size_t)row_i * 9 + (t - 204)];
    if (t >= 213 && t < 216) trans_s[t - 213] = trans[(size_t)row_i * 3 + (t - 213)];

    const float rs3C = 0.14433756729740643f; // sqrt(1/48)
    const float rs3  = 0.5773502691896258f;  // sqrt(1/3)

    // ---- Phase 1: bias = pair @ wb.T + bb  -> attn_s[h][j] = rs3*bias (init)
    // thread decomposition: hq = t&3 (3 heads each), subB = (t>>2)&7 (16-float d-chunk), ribB = t>>5 (row)
    {
        const int hq = t & 3;
        const int subB = (t >> 2) & 7;
        const int ribB = t >> 5;
        float wreg[3][16];
        #pragma unroll
        for (int hh = 0; hh < 3; ++hh) {
            const float* wrow = wb + (size_t)(hq * 3 + hh) * CZD + subB * 16;
            float4 w0 = *(const float4*)(wrow);
            float4 w1 = *(const float4*)(wrow + 4);
            float4 w2 = *(const float4*)(wrow + 8);
            float4 w3 = *(const float4*)(wrow + 12);
            wreg[hh][0]=w0.x; wreg[hh][1]=w0.y; wreg[hh][2]=w0.z; wreg[hh][3]=w0.w;
            wreg[hh][4]=w1.x; wreg[hh][5]=w1.y; wreg[hh][6]=w1.z; wreg[hh][7]=w1.w;
            wreg[hh][8]=w2.x; wreg[hh][9]=w2.y; wreg[hh][10]=w2.z; wreg[hh][11]=w2.w;
            wreg[hh][12]=w3.x; wreg[hh][13]=w3.y; wreg[hh][14]=w3.z; wreg[hh][15]=w3.w;
        }
        float bbv[3];
        #pragma unroll
        for (int hh = 0; hh < 3; ++hh) bbv[hh] = bb[hq * 3 + hh];

        for (int it = 0; it < 64; ++it) {
            int j = it * 8 + ribB;
            const float* prow = pair + ((size_t)row_i * NN + j) * CZD + subB * 16;
            float4 pA = *(const float4*)(prow);
            float4 pB = *(const float4*)(prow + 4);
            float4 pC = *(const float4*)(prow + 8);
            float4 pD = *(const float4*)(prow + 12);
            float acc[3];
            #pragma unroll
            for (int hh = 0; hh < 3; ++hh) {
                const float* wr = wreg[hh];
                acc[hh] = pA.x*wr[0] + pA.y*wr[1] + pA.z*wr[2] + pA.w*wr[3]
                        + pB.x*wr[4] + pB.y*wr[5] + pB.z*wr[6] + pB.w*wr[7]
                        + pC.x*wr[8] + pC.y*wr[9] + pC.z*wr[10] + pC.w*wr[11]
                        + pD.x*wr[12] + pD.y*wr[13] + pD.z*wr[14] + pD.w*wr[15];
            }
            // reduce across subB (t bits 2..4): xor offsets 4, 8, 16
            #pragma unroll
            for (int off = 4; off <= 16; off <<= 1) {
                #pragma unroll
                for (int hh = 0; hh < 3; ++hh) acc[hh] += __shfl_xor(acc[hh], off, 64);
            }
            if (subB == 0) {
                #pragma unroll
                for (int hh = 0; hh < 3; ++hh)
                    attn_s[hq * 3 + hh][j] = rs3 * (acc[hh] + bbv[hh]);
            }
        }
    }
    __syncthreads();

    // ---- Phase 2: logits += rs3C*qk + coef*d2  (12*512 tasks)
    for (int kk = 0; kk < 24; ++kk) {
        int idx = kk * 256 + t;
        int h = idx >> 9, j = idx & 511;
        const float* krow = kws + (bbase + j) * HC + h * 16;
        float qk = 0.f;
        #pragma unroll
        for (int c4 = 0; c4 < 4; ++c4) {
            float4 k4 = *(const float4*)(krow + c4 * 4);
            const float* qr = &q_s[h * 16 + c4 * 4];
            qk += k4.x * qr[0] + k4.y * qr[1] + k4.z * qr[2] + k4.w * qr[3];
        }
        const float* kgrow = kgws + (bbase + j) * QPDIM + h * 12;
        const float* qgr = &qg_s[h * 12];
        float d2 = 0.f;
        #pragma unroll
        for (int c4 = 0; c4 < 3; ++c4) {
            float4 kg4 = *(const float4*)(kgrow + c4 * 4);
            float4 qd  = *(const float4*)(qgr + c4 * 4);
            float d0 = qd.x - kg4.x, d1 = qd.y - kg4.y, d2c = qd.z - kg4.z, d3 = qd.w - kg4.w;
            d2 += d0 * d0 + d1 * d1 + d2c * d2c + d3 * d3;
        }
        attn_s[h][j] += rs3C * qk + coef_s[h] * d2;
    }
    __syncthreads();

    // ---- Phase 3: softmax (wave w -> heads 3w..3w+2)
    {
        int w = t >> 6, lane = t & 63;
        for (int hh = 0; hh < 3; ++hh) {
            int h = w * 3 + hh;
            float m = -1e30f;
            for (int j = lane; j < NN; j += 64) m = fmaxf(m, attn_s[h][j]);
            #pragma unroll
            for (int off = 32; off >= 1; off >>= 1) m = fmaxf(m, __shfl_xor(m, off, 64));
            float s = 0.f;
            for (int j = lane; j < NN; j += 64) { float e = __expf(attn_s[h][j] - m); attn_s[h][j] = e; s += e; }
            #pragma unroll
            for (int off = 32; off >= 1; off >>= 1) s += __shfl_xor(s, off, 64);
            float inv = 1.0f / s;
            for (int j = lane; j < NN; j += 64) attn_s[h][j] *= inv;
        }
    }
    __syncthreads();

    float* frow = feats + (size_t)row_i * FEATD;

    // ---- Phase 4: out_scalar + rp_g via vall (coalesced float4, 2-way j-split)
    {
        const int g4 = t & 127;
        const int jp = t >> 7;
        const int comp = 4 * g4;
        const bool active = (g4 < 120);
        float ax = 0.f, ay = 0.f, az = 0.f, aw = 0.f;
        if (active) {
            const int h5 = (comp < 192) ? (comp >> 4) : ((comp - 192) / 24);
            const float* arow = attn_s[h5];
            const float* vbase = vall + bbase * VALLD + comp;
            for (int jj = 0; jj < 256; ++jj) {
                int j = 2 * jj + jp;
                float a = arow[j];
                float4 v4 = *(const float4*)(vbase + (size_t)j * VALLD);
                ax += a * v4.x; ay += a * v4.y; az += a * v4.z; aw += a * v4.w;
            }
        }
        __syncthreads();
        if (jp == 1 && active) {
            float4 st = {ax, ay, az, aw};
            *(float4*)(&red_s[comp]) = st;
        }
        __syncthreads();
        if (jp == 0 && active) {
            float4 rd = *(const float4*)(&red_s[comp]);
            float4 o4 = {ax + rd.x, ay + rd.y, az + rd.z, aw + rd.w};
            if (comp < 192) *(float4*)(frow + comp) = o4;
            else            *(float4*)(&rp2_s[comp - 192]) = o4;
        }
    }
    __syncthreads();

    // ---- Phase 5: out_pair (coalesced float4; thread: 3 heads x 4 d; parity split over j)
    {
        const int q6 = t >> 6;          // head triple
        const int p6 = (t >> 5) & 1;    // j parity
        const int g6 = t & 31;          // d group
        float acc[3][4] = {{0}};
        const float* prow6 = pair + (size_t)row_i * NN * CZD + 4 * g6;
        for (int jj = 0; jj < 256; ++jj) {
            int j = 2 * jj + p6;
            float4 p4 = *(const float4*)(prow6 + (size_t)j * CZD);
            #pragma unroll
            for (int hh = 0; hh < 3; ++hh) {
                float a = attn_s[3 * q6 + hh][j];
                acc[hh][0] += a * p4.x; acc[hh][1] += a * p4.y;
                acc[hh][2] += a * p4.z; acc[hh][3] += a * p4.w;
            }
        }
        #pragma unroll
        for (int hh = 0; hh < 3; ++hh)
            #pragma unroll
            for (int c = 0; c < 4; ++c)
                acc[hh][c] += __shfl_xor(acc[hh][c], 32, 64);
        if (p6 == 0) {
            #pragma unroll
            for (int hh = 0; hh < 3; ++hh) {
                float4 o4 = {acc[hh][0], acc[hh][1], acc[hh][2], acc[hh][3]};
                *(float4*)(frow + 576 + (size_t)(3 * q6 + hh) * CZD + 4 * g6) = o4;
            }
        }
    }

    // ---- Phase 6: rp_l + norms (rp2_s ready since barrier after phase 4)
    if (t < 96) {
        int h = t >> 3, p = t & 7;
        float d0 = rp2_s[h * 24 + p * 3 + 0] - trans_s[0];
        float d1 = rp2_s[h * 24 + p * 3 + 1] - trans_s[1];
        float d2v = rp2_s[h * 24 + p * 3 + 2] - trans_s[2];
        float l0 = rot_s[0] * d0 + rot_s[3] * d1 + rot_s[6] * d2v;
        float l1 = rot_s[1] * d0 + rot_s[4] * d1 + rot_s[7] * d2v;
        float l2 = rot_s[2] * d0 + rot_s[5] * d1 + rot_s[8] * d2v;
        float nrm = sqrtf(l0 * l0 + l1 * l1 + l2 * l2 + 1e-8f);
        frow[192 + h * 8 + p] = l0;
        frow[288 + h * 8 + p] = l1;
        frow[384 + h * 8 + p] = l2;
        frow[480 + h * 8 + p] = nrm;
    }
}

// ---------------- Kernel 3: out = feats @ wo.T + bo ----------------
__global__ __launch_bounds__(256) void k_out(
    const float* __restrict__ featsws, const float* __restrict__ wo, const float* __restrict__ bo,
    float* __restrict__ out)
{
    __shared__ float fs[4][FEATD];
    int t = threadIdx.x;
    int row0 = blockIdx.x * 4;
    for (int idx = t; idx < 4 * FEATD; idx += 256) {
        int r = idx / FEATD, k = idx % FEATD;
        fs[r][k] = featsws[(size_t)(row0 + r) * FEATD + k];
    }
    __syncthreads();
    for (int o = t; o < CSD; o += 256) {
        const float* wrow = wo + (size_t)o * FEATD;
        float a0 = 0.f, a1 = 0.f, a2 = 0.f, a3 = 0.f;
        for (int k = 0; k < FEATD; k += 4) {
            float4 w4 = *(const float4*)(wrow + k);
            float4 f0 = *(const float4*)(&fs[0][k]);
            float4 f1 = *(const float4*)(&fs[1][k]);
            float4 f2 = *(const float4*)(&fs[2][k]);
            float4 f3 = *(const float4*)(&fs[3][k]);
            a0 += w4.x * f0.x + w4.y * f0.y + w4.z * f0.z + w4.w * f0.w;
            a1 += w4.x * f1.x + w4.y * f1.y + w4.z * f1.z + w4.w * f1.w;
            a2 += w4.x * f2.x + w4.y * f2.y + w4.z * f2.z + w4.w * f2.w;
            a3 += w4.x * f3.x + w4.y * f3.y + w4.z * f3.z + w4.w * f3.w;
        }
        float bv = bo[o];
        out[(size_t)(row0 + 0) * CSD + o] = a0 + bv;
        out[(size_t)(row0 + 1) * CSD + o] = a1 + bv;
        out[(size_t)(row0 + 2) * CSD + o] = a2 + bv;
        out[(size_t)(row0 + 3) * CSD + o] = a3 + bv;
    }
}

extern "C" void kernel_launch(void* const* d_in, const int* in_sizes, int n_in,
                              void* d_out, int out_size, void* d_ws, size_t ws_size,
                              hipStream_t stream) {
    const float* single = (const float*)d_in[0];
    const float* pair   = (const float*)d_in[1];
    const float* rot    = (const float*)d_in[2];
    const float* trans  = (const float*)d_in[3];
    const float* wq     = (const float*)d_in[4];
    const float* bq     = (const float*)d_in[5];
    const float* wkv    = (const float*)d_in[6];
    const float* bkv    = (const float*)d_in[7];
    const float* wqp    = (const float*)d_in[8];
    const float* bqp    = (const float*)d_in[9];
    const float* wkvp   = (const float*)d_in[10];
    const float* bkvp   = (const float*)d_in[11];
    const float* wb     = (const float*)d_in[12];
    const float* bb     = (const float*)d_in[13];
    const float* wo     = (const float*)d_in[14];
    const float* bo     = (const float*)d_in[15];
    const float* hw     = (const float*)d_in[16];
    float* out = (float*)d_out;

    float* ws = (float*)d_ws;
    float* qws    = ws;                 // 2*512*192  = 196608
    float* kws    = qws  + 196608;      // 196608
    float* vall   = kws  + 196608;      // 2*512*512  = 524288
    float* qgws   = vall + 524288;      // 2*512*144  = 147456
    float* kgws   = qgws + 147456;      // 147456
    float* featsws= kgws + 147456;      // 2*512*2112 = 2162688
    // total: 3,375,104 floats = 13.5 MB

    hipLaunchKernelGGL(k_proj, dim3(256), dim3(256), 0, stream,
                       single, rot, trans, wq, bq, wkv, bkv, wqp, bqp, wkvp, bkvp,
                       qws, kws, vall, qgws, kgws);
    hipLaunchKernelGGL(k_attn, dim3(1024), dim3(256), 0, stream,
                       pair, rot, trans, hw, wb, bb, qws, kws, vall, qgws, kgws, featsws);
    hipLaunchKernelGGL(k_out, dim3(256), dim3(256), 0, stream, featsws, wo, bo, out);
}

// Round 4
// 325.591 us; speedup vs baseline: 1.9494x; 1.3762x over previous
//
#include <hip/hip_runtime.h>
#include <hip/hip_bf16.h>
#include <math.h>

#define NB 2
#define NN 512
#define CSD 384
#define CZD 128
#define NH 12
#define NC 16
#define NPQ 4
#define NPV 8
// derived
#define HC 192      // H*C
#define QPDIM 144   // 3*H*PQ
#define FEATD 2112  // H*C + H*PV*4 + H*CZ
#define VALLD 512   // padded 480 (192 scalar v + 288 vg)

typedef __attribute__((ext_vector_type(8))) short short8;
typedef __attribute__((ext_vector_type(4))) float f32x4;

static __device__ inline unsigned short f2bf(float x) {
    __hip_bfloat16 h = __float2bfloat16(x);
    return *reinterpret_cast<unsigned short*>(&h);
}

// ---------------- k_cvt: pack f32 -> bf16 (single, weights, wo) ----------------
// region sizes (elements)
#define R_S0 393216              // single
#define R_S1 (R_S0 + 73728)      // wq
#define R_S2 (R_S1 + 147456)     // wkv
#define R_S3 (R_S2 + 55296)      // wqp
#define R_S4 (R_S3 + 165888)     // wkvp
#define R_S5 (R_S4 + 811008)     // wo   -> total 1,646,592 = 1608*256*4
__global__ __launch_bounds__(256) void k_cvt(
    const float* __restrict__ single, const float* __restrict__ wq,
    const float* __restrict__ wkv, const float* __restrict__ wqp,
    const float* __restrict__ wkvp, const float* __restrict__ wo,
    unsigned short* __restrict__ singleb, unsigned short* __restrict__ wallb,
    unsigned short* __restrict__ wob)
{
    int gid = blockIdx.x * 256 + threadIdx.x;
    int e = gid * 4;
    if (e >= R_S5) return;
    const float* src; unsigned short* dst;
    if (e < R_S0)      { src = single + e;          dst = singleb + e; }
    else if (e < R_S1) { src = wq + (e - R_S0);     dst = wallb + (e - R_S0); }
    else if (e < R_S2) { src = wkv + (e - R_S1);    dst = wallb + 73728 + (e - R_S1); }
    else if (e < R_S3) { src = wqp + (e - R_S2);    dst = wallb + 221184 + (e - R_S2); }
    else if (e < R_S4) { src = wkvp + (e - R_S3);   dst = wallb + 276480 + (e - R_S3); }
    else               { src = wo + (e - R_S4);     dst = wob + (e - R_S4); }
    float4 v = *(const float4*)src;
    ushort4 o;
    o.x = f2bf(v.x); o.y = f2bf(v.y); o.z = f2bf(v.z); o.w = f2bf(v.w);
    *(ushort4*)dst = o;
}

// ---------------- k_gemm1: projraw = single_bf16 @ wall_bf16^T ----------------
// M=1024, N=1152, K=384. grid (64, 18), 4 waves; wave = 16x16 tile.
__global__ __launch_bounds__(256) void k_gemm1(
    const unsigned short* __restrict__ A, const unsigned short* __restrict__ Bm,
    float* __restrict__ Cr)
{
    int w = threadIdx.x >> 6, lane = threadIdx.x & 63;
    int rt = blockIdx.x;
    int ct = blockIdx.y * 4 + w;
    int r = lane & 15, kq = lane >> 4;
    const unsigned short* ap = A  + (size_t)(rt * 16 + r) * 384 + kq * 8;
    const unsigned short* bp = Bm + (size_t)(ct * 16 + r) * 384 + kq * 8;
    f32x4 acc = {0.f, 0.f, 0.f, 0.f};
    #pragma unroll 4
    for (int ks = 0; ks < 12; ++ks) {
        short8 av = *(const short8*)(ap + ks * 32);
        short8 bv = *(const short8*)(bp + ks * 32);
        acc = __builtin_amdgcn_mfma_f32_16x16x32_bf16(av, bv, acc, 0, 0, 0);
    }
    int crow = rt * 16 + kq * 4;
    int ccol = ct * 16 + r;
    #pragma unroll
    for (int i = 0; i < 4; ++i)
        Cr[(size_t)(crow + i) * 1152 + ccol] = acc[i];
}

// ---------------- k_post: bias + split + rotations ----------------
__global__ __launch_bounds__(256) void k_post(
    const float* __restrict__ praw, const float* __restrict__ rot, const float* __restrict__ trans,
    const float* __restrict__ bq, const float* __restrict__ bkv,
    const float* __restrict__ bqp, const float* __restrict__ bkvp,
    float* __restrict__ qws, float* __restrict__ kws, float* __restrict__ vall,
    float* __restrict__ qgws, float* __restrict__ kgws)
{
    __shared__ float s_qp[QPDIM];
    __shared__ float s_kvp[432];
    int t = threadIdx.x;
    int row = blockIdx.x;
    const float* pr = praw + (size_t)row * 1152;
    for (int idx = t; idx < 1152; idx += 256) {
        float v = pr[idx];
        if (idx < 192) {
            qws[(size_t)row * HC + idx] = v + bq[idx];
        } else if (idx < 576) {
            int f = idx - 192; float x = v + bkv[f];
            int h = f >> 5, cc = f & 31;
            if (cc < 16) kws[(size_t)row * HC + h * 16 + cc] = x;
            else         vall[(size_t)row * VALLD + h * 16 + cc - 16] = x;
        } else if (idx < 720) {
            int f = idx - 576; s_qp[f] = v + bqp[f];
        } else {
            int f = idx - 720; s_kvp[f] = v + bkvp[f];
        }
    }
    __syncthreads();
    if (t < 192) {
        const float* R = rot + (size_t)row * 9;
        const float* T = trans + (size_t)row * 3;
        float lx, ly, lz; float* dst;
        if (t < 48) {
            lx = s_qp[t]; ly = s_qp[48 + t]; lz = s_qp[96 + t];
            dst = qgws + ((size_t)row * 48 + t) * 3;
        } else if (t < 96) {
            int idx = t - 48; int h = idx >> 2, p = idx & 3;
            int fb = h * 12 + p;
            lx = s_kvp[fb]; ly = s_kvp[144 + fb]; lz = s_kvp[288 + fb];
            dst = kgws + ((size_t)row * 48 + idx) * 3;
        } else {
            int idx = t - 96; int h = idx >> 3, p = idx & 7;
            int fb = h * 12 + 4 + p;
            lx = s_kvp[fb]; ly = s_kvp[144 + fb]; lz = s_kvp[288 + fb];
            dst = vall + (size_t)row * VALLD + 192 + idx * 3;
        }
        dst[0] = R[0] * lx + R[1] * ly + R[2] * lz + T[0];
        dst[1] = R[3] * lx + R[4] * ly + R[5] * lz + T[1];
        dst[2] = R[6] * lx + R[7] * ly + R[8] * lz + T[2];
    }
}

// ---------------- k_logits: bias + qk + d2 -> logits ws ----------------
// grid 4096: (row_i, jc) jc in 0..3, 128 j's each
__global__ __launch_bounds__(256) void k_logits(
    const float* __restrict__ pair, const float* __restrict__ hw,
    const float* __restrict__ wb, const float* __restrict__ bb,
    const float* __restrict__ qws, const float* __restrict__ kws,
    const float* __restrict__ qgws, const float* __restrict__ kgws,
    float* __restrict__ logits)
{
    __shared__ float attn_s[NH][132];
    __shared__ float q_s[HC];
    __shared__ float qg_s[QPDIM];
    __shared__ float coef_s[NH];
    const int t = threadIdx.x;
    const int row_i = blockIdx.x >> 2;
    const int jc = blockIdx.x & 3;
    const int j0 = jc * 128;
    const int b = row_i >> 9;
    const size_t bbase = (size_t)b * NN;

    if (t < HC)   q_s[t]  = qws[(size_t)row_i * HC + t];
    if (t < QPDIM) qg_s[t] = qgws[(size_t)row_i * QPDIM + t];
    if (t >= 192 && t < 204) {
        int h = t - 192; float x = hw[h];
        coef_s[h] = -0.5f * 0.13608276348795434f * log1pf(expf(x));
    }

    const float rs3C = 0.14433756729740643f; // sqrt(1/48)
    const float rs3  = 0.5773502691896258f;  // sqrt(1/3)

    // Phase A: bias
    {
        const int hq = t & 3;
        const int subB = (t >> 2) & 7;
        const int ribB = t >> 5;
        float wreg[3][16];
        #pragma unroll
        for (int hh = 0; hh < 3; ++hh) {
            const float* wrow = wb + (size_t)(hq * 3 + hh) * CZD + subB * 16;
            float4 w0 = *(const float4*)(wrow);
            float4 w1 = *(const float4*)(wrow + 4);
            float4 w2 = *(const float4*)(wrow + 8);
            float4 w3 = *(const float4*)(wrow + 12);
            wreg[hh][0]=w0.x; wreg[hh][1]=w0.y; wreg[hh][2]=w0.z; wreg[hh][3]=w0.w;
            wreg[hh][4]=w1.x; wreg[hh][5]=w1.y; wreg[hh][6]=w1.z; wreg[hh][7]=w1.w;
            wreg[hh][8]=w2.x; wreg[hh][9]=w2.y; wreg[hh][10]=w2.z; wreg[hh][11]=w2.w;
            wreg[hh][12]=w3.x; wreg[hh][13]=w3.y; wreg[hh][14]=w3.z; wreg[hh][15]=w3.w;
        }
        float bbv[3];
        #pragma unroll
        for (int hh = 0; hh < 3; ++hh) bbv[hh] = bb[hq * 3 + hh];

        for (int it = 0; it < 16; ++it) {
            int jj = it * 8 + ribB;
            const float* prow = pair + ((size_t)row_i * NN + j0 + jj) * CZD + subB * 16;
            float4 pA = *(const float4*)(prow);
            float4 pB = *(const float4*)(prow + 4);
            float4 pC = *(const float4*)(prow + 8);
            float4 pD = *(const float4*)(prow + 12);
            float acc[3];
            #pragma unroll
            for (int hh = 0; hh < 3; ++hh) {
                const float* wr = wreg[hh];
                acc[hh] = pA.x*wr[0] + pA.y*wr[1] + pA.z*wr[2] + pA.w*wr[3]
                        + pB.x*wr[4] + pB.y*wr[5] + pB.z*wr[6] + pB.w*wr[7]
                        + pC.x*wr[8] + pC.y*wr[9] + pC.z*wr[10] + pC.w*wr[11]
                        + pD.x*wr[12] + pD.y*wr[13] + pD.z*wr[14] + pD.w*wr[15];
            }
            #pragma unroll
            for (int off = 4; off <= 16; off <<= 1) {
                #pragma unroll
                for (int hh = 0; hh < 3; ++hh) acc[hh] += __shfl_xor(acc[hh], off, 64);
            }
            if (subB == 0) {
                #pragma unroll
                for (int hh = 0; hh < 3; ++hh)
                    attn_s[hq * 3 + hh][jj] = rs3 * (acc[hh] + bbv[hh]);
            }
        }
    }
    __syncthreads();

    // Phase B: qk + d2, write logits
    #pragma unroll
    for (int it = 0; it < 6; ++it) {
        int idx = it * 256 + t;
        int h = idx >> 7, jj = idx & 127;
        int j = j0 + jj;
        const float* krow = kws + (bbase + j) * HC + h * 16;
        float qk = 0.f;
        #pragma unroll
        for (int c4 = 0; c4 < 4; ++c4) {
            float4 k4 = *(const float4*)(krow + c4 * 4);
            const float* qr = &q_s[h * 16 + c4 * 4];
            qk += k4.x * qr[0] + k4.y * qr[1] + k4.z * qr[2] + k4.w * qr[3];
        }
        const float* kgrow = kgws + (bbase + j) * QPDIM + h * 12;
        const float* qgr = &qg_s[h * 12];
        float d2 = 0.f;
        #pragma unroll
        for (int c4 = 0; c4 < 3; ++c4) {
            float4 kg4 = *(const float4*)(kgrow + c4 * 4);
            float4 qd  = *(const float4*)(qgr + c4 * 4);
            float d0 = qd.x - kg4.x, d1 = qd.y - kg4.y, d2c = qd.z - kg4.z, d3 = qd.w - kg4.w;
            d2 += d0 * d0 + d1 * d1 + d2c * d2c + d3 * d3;
        }
        logits[((size_t)row_i * NH + h) * NN + j] = attn_s[h][jj] + rs3C * qk + coef_s[h] * d2;
    }
}

// ---------------- k_av: softmax + AV + out_pair + rp_l -> feats (bf16) ----------------
// grid 2048: (row_i, half)
__global__ __launch_bounds__(256) void k_av(
    const float* __restrict__ pair, const float* __restrict__ rot, const float* __restrict__ trans,
    const float* __restrict__ logits, const float* __restrict__ vall,
    unsigned short* __restrict__ featsb)
{
    __shared__ float attn6[6][516];
    __shared__ float redbuf[3072];   // vall phase: [4][256]; out_pair: [4][6][32] float4
    __shared__ float rp2_s[144];
    __shared__ float rot_s[9], trans_s[3];

    const int t = threadIdx.x;
    const int row_i = blockIdx.x >> 1;
    const int hf = blockIdx.x & 1;
    const int h0 = 6 * hf;
    const int b = row_i >> 9;
    const size_t bbase = (size_t)b * NN;
    const int w = t >> 6, lane = t & 63;

    if (t < 9) rot_s[t] = rot[(size_t)row_i * 9 + t];
    if (t >= 9 && t < 12) trans_s[t - 9] = trans[(size_t)row_i * 3 + (t - 9)];

    // softmax (wave w handles heads w, w+4 of the local 6)
    for (int hh = w; hh < 6; hh += 4) {
        const float* lp = logits + ((size_t)row_i * NH + h0 + hh) * NN;
        float vreg[8];
        float m = -1e30f;
        #pragma unroll
        for (int s = 0; s < 8; ++s) { vreg[s] = lp[lane + 64 * s]; m = fmaxf(m, vreg[s]); }
        #pragma unroll
        for (int off = 32; off >= 1; off >>= 1) m = fmaxf(m, __shfl_xor(m, off, 64));
        float ssum = 0.f;
        #pragma unroll
        for (int s = 0; s < 8; ++s) { vreg[s] = __expf(vreg[s] - m); ssum += vreg[s]; }
        #pragma unroll
        for (int off = 32; off >= 1; off >>= 1) ssum += __shfl_xor(ssum, off, 64);
        float inv = 1.0f / ssum;
        #pragma unroll
        for (int s = 0; s < 8; ++s) attn6[hh][lane + 64 * s] = vreg[s] * inv;
    }
    __syncthreads();

    unsigned short* frow = featsb + (size_t)row_i * FEATD;

    // ---- vall phase: out_scalar (96) + rp_g (144) for 6 heads; 4-way j split
    {
        const int g4 = t & 63;
        const int jp = t >> 6;
        const bool active = (g4 < 60);
        const int c = 4 * g4;
        int arow = 0, vcol = 0;
        if (c < 96) { arow = c >> 4; vcol = h0 * 16 + c; }
        else        { int c2 = c - 96; arow = c2 / 24; vcol = 192 + h0 * 24 + c2; }
        float ax = 0.f, ay = 0.f, az = 0.f, aw = 0.f;
        if (active) {
            const float* vb = vall + bbase * VALLD + vcol;
            const float* ar = attn6[arow];
            for (int jj = 0; jj < 128; ++jj) {
                int j = 4 * jj + jp;
                float a = ar[j];
                float4 v4 = *(const float4*)(vb + (size_t)j * VALLD);
                ax += a * v4.x; ay += a * v4.y; az += a * v4.z; aw += a * v4.w;
            }
        }
        if (jp > 0 && active) {
            float4 st = {ax, ay, az, aw};
            *(float4*)&redbuf[jp * 256 + 4 * g4] = st;
        }
        __syncthreads();
        if (jp == 0 && active) {
            float4 r1 = *(const float4*)&redbuf[1 * 256 + 4 * g4];
            float4 r2 = *(const float4*)&redbuf[2 * 256 + 4 * g4];
            float4 r3 = *(const float4*)&redbuf[3 * 256 + 4 * g4];
            float o0 = ax + r1.x + r2.x + r3.x;
            float o1 = ay + r1.y + r2.y + r3.y;
            float o2 = az + r1.z + r2.z + r3.z;
            float o3 = aw + r1.w + r2.w + r3.w;
            if (c < 96) {
                ushort4 ov; ov.x = f2bf(o0); ov.y = f2bf(o1); ov.z = f2bf(o2); ov.w = f2bf(o3);
                *(ushort4*)(frow + h0 * 16 + c) = ov;
            } else {
                int c2 = c - 96;
                rp2_s[c2] = o0; rp2_s[c2 + 1] = o1; rp2_s[c2 + 2] = o2; rp2_s[c2 + 3] = o3;
            }
        }
        __syncthreads();
    }

    // ---- out_pair: 6 heads x 128 d; 8-way j split; cross-wave reduce in redbuf
    {
        const int g6 = t & 31;
        const int jp8 = t >> 5;
        float acc[6][4] = {{0.f}};
        const float* prow = pair + (size_t)row_i * NN * CZD + 4 * g6;
        for (int jj = 0; jj < 64; ++jj) {
            int j = 8 * jj + jp8;
            float4 p4 = *(const float4*)(prow + (size_t)j * CZD);
            #pragma unroll
            for (int hh = 0; hh < 6; ++hh) {
                float a = attn6[hh][j];
                acc[hh][0] += a * p4.x; acc[hh][1] += a * p4.y;
                acc[hh][2] += a * p4.z; acc[hh][3] += a * p4.w;
            }
        }
        #pragma unroll
        for (int hh = 0; hh < 6; ++hh)
            #pragma unroll
            for (int cc = 0; cc < 4; ++cc)
                acc[hh][cc] += __shfl_xor(acc[hh][cc], 32, 64);
        if (lane < 32) {
            float4* r2p = (float4*)redbuf;   // [4 waves][6 heads][32 g] = 768 float4
            #pragma unroll
            for (int hh = 0; hh < 6; ++hh) {
                float4 st = {acc[hh][0], acc[hh][1], acc[hh][2], acc[hh][3]};
                r2p[(w * 6 + hh) * 32 + g6] = st;
            }
        }
        __syncthreads();
        if (t < 192) {
            int hh = t >> 5, g = t & 31;
            const float4* r2p = (const float4*)redbuf;
            float4 s0 = r2p[(0 * 6 + hh) * 32 + g];
            float4 s1 = r2p[(1 * 6 + hh) * 32 + g];
            float4 s2 = r2p[(2 * 6 + hh) * 32 + g];
            float4 s3 = r2p[(3 * 6 + hh) * 32 + g];
            ushort4 ov;
            ov.x = f2bf(s0.x + s1.x + s2.x + s3.x);
            ov.y = f2bf(s0.y + s1.y + s2.y + s3.y);
            ov.z = f2bf(s0.z + s1.z + s2.z + s3.z);
            ov.w = f2bf(s0.w + s1.w + s2.w + s3.w);
            *(ushort4*)(frow + 576 + (size_t)(h0 + hh) * CZD + 4 * g) = ov;
        }
    }

    // ---- rp_l + norms for local 6 heads
    if (t < 48) {
        int h = t >> 3, p = t & 7;
        float d0 = rp2_s[h * 24 + p * 3 + 0] - trans_s[0];
        float d1 = rp2_s[h * 24 + p * 3 + 1] - trans_s[1];
        float d2v = rp2_s[h * 24 + p * 3 + 2] - trans_s[2];
        float l0 = rot_s[0] * d0 + rot_s[3] * d1 + rot_s[6] * d2v;
        float l1 = rot_s[1] * d0 + rot_s[4] * d1 + rot_s[7] * d2v;
        float l2 = rot_s[2] * d0 + rot_s[5] * d1 + rot_s[8] * d2v;
        float nrm = sqrtf(l0 * l0 + l1 * l1 + l2 * l2 + 1e-8f);
        int hp = (h0 + h) * 8 + p;
        frow[192 + hp] = f2bf(l0);
        frow[288 + hp] = f2bf(l1);
        frow[384 + hp] = f2bf(l2);
        frow[480 + hp] = f2bf(nrm);
    }
}

// ---------------- k_gemm2: out = feats_bf16 @ wo_bf16^T + bo ----------------
// M=1024, N=384, K=2112. grid (64, 6), 4 waves; wave = 16x16 tile.
__global__ __launch_bounds__(256) void k_gemm2(
    const unsigned short* __restrict__ A, const unsigned short* __restrict__ Bm,
    const float* __restrict__ bo, float* __restrict__ out)
{
    int w = threadIdx.x >> 6, lane = threadIdx.x & 63;
    int rt = blockIdx.x;
    int ct = blockIdx.y * 4 + w;
    int r = lane & 15, kq = lane >> 4;
    const unsigned short* ap = A  + (size_t)(rt * 16 + r) * FEATD + kq * 8;
    const unsigned short* bp = Bm + (size_t)(ct * 16 + r) * FEATD + kq * 8;
    f32x4 acc = {0.f, 0.f, 0.f, 0.f};
    #pragma unroll 2
    for (int ks = 0; ks < 66; ++ks) {
        short8 av = *(const short8*)(ap + ks * 32);
        short8 bv = *(const short8*)(bp + ks * 32);
        acc = __builtin_amdgcn_mfma_f32_16x16x32_bf16(av, bv, acc, 0, 0, 0);
    }
    int crow = rt * 16 + kq * 4;
    int ccol = ct * 16 + r;
    float bv = bo[ccol];
    #pragma unroll
    for (int i = 0; i < 4; ++i)
        out[(size_t)(crow + i) * CSD + ccol] = acc[i] + bv;
}

extern "C" void kernel_launch(void* const* d_in, const int* in_sizes, int n_in,
                              void* d_out, int out_size, void* d_ws, size_t ws_size,
                              hipStream_t stream) {
    const float* single = (const float*)d_in[0];
    const float* pair   = (const float*)d_in[1];
    const float* rot    = (const float*)d_in[2];
    const float* trans  = (const float*)d_in[3];
    const float* wq     = (const float*)d_in[4];
    const float* bq     = (const float*)d_in[5];
    const float* wkv    = (const float*)d_in[6];
    const float* bkv    = (const float*)d_in[7];
    const float* wqp    = (const float*)d_in[8];
    const float* bqp    = (const float*)d_in[9];
    const float* wkvp   = (const float*)d_in[10];
    const float* bkvp   = (const float*)d_in[11];
    const float* wb     = (const float*)d_in[12];
    const float* bb     = (const float*)d_in[13];
    const float* wo     = (const float*)d_in[14];
    const float* bo     = (const float*)d_in[15];
    const float* hw     = (const float*)d_in[16];
    float* out = (float*)d_out;

    float* ws = (float*)d_ws;
    // f32-slot layout (projraw aliases logits: disjoint lifetimes)
    float* logits  = ws;                      // 6,291,456 f32 (25 MB)
    float* projraw = ws;                      // 1,179,648 f32 (alias, consumed before logits written)
    float* vall    = ws + 6291456;            // 524,288
    float* qws     = vall + 524288;           // 196,608
    float* kws     = qws + 196608;            // 196,608
    float* qgws    = kws + 196608;            // 147,456
    float* kgws    = qgws + 147456;           // 147,456
    unsigned short* featsb  = (unsigned short*)(kgws + 147456);   // 2,162,688 bf16
    unsigned short* singleb = (unsigned short*)((float*)featsb + 1081344); // 393,216 bf16
    unsigned short* wallb   = (unsigned short*)((float*)singleb + 196608); // 442,368 bf16
    unsigned short* wob     = (unsigned short*)((float*)wallb + 221184);   // 811,008 bf16
    // total 9,408,512 f32 = 37.6 MB

    hipLaunchKernelGGL(k_cvt, dim3(1608), dim3(256), 0, stream,
                       single, wq, wkv, wqp, wkvp, wo, singleb, wallb, wob);
    hipLaunchKernelGGL(k_gemm1, dim3(64, 18), dim3(256), 0, stream, singleb, wallb, projraw);
    hipLaunchKernelGGL(k_post, dim3(1024), dim3(256), 0, stream,
                       projraw, rot, trans, bq, bkv, bqp, bkvp, qws, kws, vall, qgws, kgws);
    hipLaunchKernelGGL(k_logits, dim3(4096), dim3(256), 0, stream,
                       pair, hw, wb, bb, qws, kws, qgws, kgws, logits);
    hipLaunchKernelGGL(k_av, dim3(2048), dim3(256), 0, stream,
                       pair, rot, trans, logits, vall, featsb);
    hipLaunchKernelGGL(k_gemm2, dim3(64, 6), dim3(256), 0, stream, featsb, wob, bo, out);
}

// Round 5
// 286.805 us; speedup vs baseline: 2.2131x; 1.1352x over previous
//
#include <hip/hip_runtime.h>
#include <hip/hip_bf16.h>
#include <math.h>

#define NB 2
#define NN 512
#define CSD 384
#define CZD 128
#define NH 12
#define NC 16
#define NPQ 4
#define NPV 8
// derived
#define HC 192      // H*C
#define QPDIM 144   // 3*H*PQ
#define FEATD 2112  // H*C + H*PV*4 + H*CZ
#define VALLD 512   // padded 480 (192 scalar v + 288 vg)

typedef __attribute__((ext_vector_type(8))) short short8;
typedef __attribute__((ext_vector_type(4))) float f32x4;

static __device__ inline unsigned short f2bf(float x) {
    __hip_bfloat16 h = __float2bfloat16(x);
    return *reinterpret_cast<unsigned short*>(&h);
}

// ---------------- k_cvt: pack f32 -> bf16 (single, weights, wo, wb-padded) ----------------
// region sizes (elements)
#define R_S0 393216              // single
#define R_S1 (R_S0 + 73728)      // wq
#define R_S2 (R_S1 + 147456)     // wkv
#define R_S3 (R_S2 + 55296)      // wqp
#define R_S4 (R_S3 + 165888)     // wkvp
#define R_S5 (R_S4 + 811008)     // wo
#define R_S6 (R_S5 + 2048)       // wbb (16x128, rows 12..15 zero) -> total 1,648,640 = 1610*256*4
__global__ __launch_bounds__(256) void k_cvt(
    const float* __restrict__ single, const float* __restrict__ wq,
    const float* __restrict__ wkv, const float* __restrict__ wqp,
    const float* __restrict__ wkvp, const float* __restrict__ wo,
    const float* __restrict__ wb,
    unsigned short* __restrict__ singleb, unsigned short* __restrict__ wallb,
    unsigned short* __restrict__ wob, unsigned short* __restrict__ wbb)
{
    int gid = blockIdx.x * 256 + threadIdx.x;
    int e = gid * 4;
    if (e >= R_S6) return;
    if (e >= R_S5) {
        int c = e - R_S5;       // 0..2047
        int hh = c >> 7;
        ushort4 o;
        if (hh < 12) {
            float4 v = *(const float4*)(wb + hh * 128 + (c & 127));
            o.x = f2bf(v.x); o.y = f2bf(v.y); o.z = f2bf(v.z); o.w = f2bf(v.w);
        } else {
            o.x = 0; o.y = 0; o.z = 0; o.w = 0;
        }
        *(ushort4*)(wbb + c) = o;
        return;
    }
    const float* src; unsigned short* dst;
    if (e < R_S0)      { src = single + e;          dst = singleb + e; }
    else if (e < R_S1) { src = wq + (e - R_S0);     dst = wallb + (e - R_S0); }
    else if (e < R_S2) { src = wkv + (e - R_S1);    dst = wallb + 73728 + (e - R_S1); }
    else if (e < R_S3) { src = wqp + (e - R_S2);    dst = wallb + 221184 + (e - R_S2); }
    else if (e < R_S4) { src = wkvp + (e - R_S3);   dst = wallb + 276480 + (e - R_S3); }
    else               { src = wo + (e - R_S4);     dst = wob + (e - R_S4); }
    float4 v = *(const float4*)src;
    ushort4 o;
    o.x = f2bf(v.x); o.y = f2bf(v.y); o.z = f2bf(v.z); o.w = f2bf(v.w);
    *(ushort4*)dst = o;
}

// ---------------- k_gemm1: projraw = single_bf16 @ wall_bf16^T ----------------
// M=1024, N=1152, K=384. grid (64, 18), 4 waves; wave = 16x16 tile.
__global__ __launch_bounds__(256) void k_gemm1(
    const unsigned short* __restrict__ A, const unsigned short* __restrict__ Bm,
    float* __restrict__ Cr)
{
    int w = threadIdx.x >> 6, lane = threadIdx.x & 63;
    int rt = blockIdx.x;
    int ct = blockIdx.y * 4 + w;
    int r = lane & 15, kq = lane >> 4;
    const unsigned short* ap = A  + (size_t)(rt * 16 + r) * 384 + kq * 8;
    const unsigned short* bp = Bm + (size_t)(ct * 16 + r) * 384 + kq * 8;
    f32x4 acc = {0.f, 0.f, 0.f, 0.f};
    #pragma unroll 4
    for (int ks = 0; ks < 12; ++ks) {
        short8 av = *(const short8*)(ap + ks * 32);
        short8 bv = *(const short8*)(bp + ks * 32);
        acc = __builtin_amdgcn_mfma_f32_16x16x32_bf16(av, bv, acc, 0, 0, 0);
    }
    int crow = rt * 16 + kq * 4;
    int ccol = ct * 16 + r;
    #pragma unroll
    for (int i = 0; i < 4; ++i)
        Cr[(size_t)(crow + i) * 1152 + ccol] = acc[i];
}

// ---------------- k_post: bias + split + rotations ----------------
__global__ __launch_bounds__(256) void k_post(
    const float* __restrict__ praw, const float* __restrict__ rot, const float* __restrict__ trans,
    const float* __restrict__ bq, const float* __restrict__ bkv,
    const float* __restrict__ bqp, const float* __restrict__ bkvp,
    float* __restrict__ qws, float* __restrict__ kws, float* __restrict__ vall,
    float* __restrict__ qgws, float* __restrict__ kgws)
{
    __shared__ float s_qp[QPDIM];
    __shared__ float s_kvp[432];
    int t = threadIdx.x;
    int row = blockIdx.x;
    const float* pr = praw + (size_t)row * 1152;
    for (int idx = t; idx < 1152; idx += 256) {
        float v = pr[idx];
        if (idx < 192) {
            qws[(size_t)row * HC + idx] = v + bq[idx];
        } else if (idx < 576) {
            int f = idx - 192; float x = v + bkv[f];
            int h = f >> 5, cc = f & 31;
            if (cc < 16) kws[(size_t)row * HC + h * 16 + cc] = x;
            else         vall[(size_t)row * VALLD + h * 16 + cc - 16] = x;
        } else if (idx < 720) {
            int f = idx - 576; s_qp[f] = v + bqp[f];
        } else {
            int f = idx - 720; s_kvp[f] = v + bkvp[f];
        }
    }
    __syncthreads();
    if (t < 192) {
        const float* R = rot + (size_t)row * 9;
        const float* T = trans + (size_t)row * 3;
        float lx, ly, lz; float* dst;
        if (t < 48) {
            lx = s_qp[t]; ly = s_qp[48 + t]; lz = s_qp[96 + t];
            dst = qgws + ((size_t)row * 48 + t) * 3;
        } else if (t < 96) {
            int idx = t - 48; int h = idx >> 2, p = idx & 3;
            int fb = h * 12 + p;
            lx = s_kvp[fb]; ly = s_kvp[144 + fb]; lz = s_kvp[288 + fb];
            dst = kgws + ((size_t)row * 48 + idx) * 3;
        } else {
            int idx = t - 96; int h = idx >> 3, p = idx & 7;
            int fb = h * 12 + 4 + p;
            lx = s_kvp[fb]; ly = s_kvp[144 + fb]; lz = s_kvp[288 + fb];
            dst = vall + (size_t)row * VALLD + 192 + idx * 3;
        }
        dst[0] = R[0] * lx + R[1] * ly + R[2] * lz + T[0];
        dst[1] = R[3] * lx + R[4] * ly + R[5] * lz + T[1];
        dst[2] = R[6] * lx + R[7] * ly + R[8] * lz + T[2];
    }
}

// ---------------- k_plog: MFMA bias + qk + d2 -> logits ----------------
// grid 4096: (row_i, jc in 0..3), 128 pair rows each
__global__ __launch_bounds__(256) void k_plog(
    const float* __restrict__ pair, const float* __restrict__ hw,
    const unsigned short* __restrict__ wbb, const float* __restrict__ bb,
    const float* __restrict__ qws, const float* __restrict__ kws,
    const float* __restrict__ qgws, const float* __restrict__ kgws,
    float* __restrict__ logits)
{
    __shared__ float bias_s[128][17];
    __shared__ float q_s[HC];
    __shared__ float qg_s[QPDIM];
    __shared__ float coef_s[NH];
    const int t = threadIdx.x;
    const int row_i = blockIdx.x >> 2;
    const int jc = blockIdx.x & 3;
    const int j0 = jc * 128;
    const int b = row_i >> 9;
    const size_t bbase = (size_t)b * NN;
    const int w = t >> 6, lane = t & 63;
    const int r = lane & 15, kq = lane >> 4;

    if (t < HC)   q_s[t]  = qws[(size_t)row_i * HC + t];
    if (t < QPDIM) qg_s[t] = qgws[(size_t)row_i * QPDIM + t];
    if (t >= 192 && t < 204) {
        int h = t - 192; float x = hw[h];
        coef_s[h] = -0.5f * 0.13608276348795434f * log1pf(expf(x));
    }

    const float rs3C = 0.14433756729740643f; // sqrt(1/48)
    const float rs3  = 0.5773502691896258f;  // sqrt(1/3)

    // ---- Phase A: bias via MFMA. 8 tiles of 16 rows; wave w does tiles w, w+4.
    {
        // B fragment: wbb[16][128], col index = r (head), k = kq*8 + ks*32
        const unsigned short* bp = wbb + r * 128 + kq * 8;
        short8 bfrag[4];
        #pragma unroll
        for (int ks = 0; ks < 4; ++ks) bfrag[ks] = *(const short8*)(bp + ks * 32);
        float bbv = (r < 12) ? bb[r] : 0.f;

        #pragma unroll
        for (int tt = 0; tt < 2; ++tt) {
            int tile = w + tt * 4;
            size_t rowg = (size_t)row_i * NN + j0 + tile * 16 + r;
            const float* ap = pair + rowg * CZD + kq * 8;
            // issue all 8 loads first (independent -> MLP)
            float4 p[8];
            #pragma unroll
            for (int ks = 0; ks < 4; ++ks) {
                p[2 * ks]     = *(const float4*)(ap + ks * 32);
                p[2 * ks + 1] = *(const float4*)(ap + ks * 32 + 4);
            }
            f32x4 acc = {0.f, 0.f, 0.f, 0.f};
            #pragma unroll
            for (int ks = 0; ks < 4; ++ks) {
                short8 av;
                av[0] = (short)f2bf(p[2*ks].x);   av[1] = (short)f2bf(p[2*ks].y);
                av[2] = (short)f2bf(p[2*ks].z);   av[3] = (short)f2bf(p[2*ks].w);
                av[4] = (short)f2bf(p[2*ks+1].x); av[5] = (short)f2bf(p[2*ks+1].y);
                av[6] = (short)f2bf(p[2*ks+1].z); av[7] = (short)f2bf(p[2*ks+1].w);
                acc = __builtin_amdgcn_mfma_f32_16x16x32_bf16(av, bfrag[ks], acc, 0, 0, 0);
            }
            // C: col = r (head), row = kq*4 + i (j within tile)
            #pragma unroll
            for (int i = 0; i < 4; ++i)
                bias_s[tile * 16 + kq * 4 + i][r] = rs3 * (acc[i] + bbv);
        }
    }
    __syncthreads();

    // ---- Phase B: qk + d2 + bias -> logits (12 h x 128 j tasks)
    #pragma unroll
    for (int it = 0; it < 6; ++it) {
        int idx = it * 256 + t;
        int h = idx >> 7, jj = idx & 127;
        int j = j0 + jj;
        const float* krow = kws + (bbase + j) * HC + h * 16;
        float qk = 0.f;
        #pragma unroll
        for (int c4 = 0; c4 < 4; ++c4) {
            float4 k4 = *(const float4*)(krow + c4 * 4);
            const float* qr = &q_s[h * 16 + c4 * 4];
            qk += k4.x * qr[0] + k4.y * qr[1] + k4.z * qr[2] + k4.w * qr[3];
        }
        const float* kgrow = kgws + (bbase + j) * QPDIM + h * 12;
        const float* qgr = &qg_s[h * 12];
        float d2 = 0.f;
        #pragma unroll
        for (int c4 = 0; c4 < 3; ++c4) {
            float4 kg4 = *(const float4*)(kgrow + c4 * 4);
            float4 qd  = *(const float4*)(qgr + c4 * 4);
            float d0 = qd.x - kg4.x, d1 = qd.y - kg4.y, d2c = qd.z - kg4.z, d3 = qd.w - kg4.w;
            d2 += d0 * d0 + d1 * d1 + d2c * d2c + d3 * d3;
        }
        logits[((size_t)row_i * NH + h) * NN + j] = bias_s[jj][h] + rs3C * qk + coef_s[h] * d2;
    }
}

// ---------------- k_av: softmax + AV + out_pair + rp_l -> feats (bf16) ----------------
// grid 2048: (row_i, half)
__global__ __launch_bounds__(256) void k_av(
    const float* __restrict__ pair, const float* __restrict__ rot, const float* __restrict__ trans,
    const float* __restrict__ logits, const float* __restrict__ vall,
    unsigned short* __restrict__ featsb)
{
    __shared__ float attn6[6][516];
    __shared__ float redbuf[3072];   // vall phase: [4][256]; out_pair: [4][6][32] float4
    __shared__ float rp2_s[144];
    __shared__ float rot_s[9], trans_s[3];

    const int t = threadIdx.x;
    const int row_i = blockIdx.x >> 1;
    const int hf = blockIdx.x & 1;
    const int h0 = 6 * hf;
    const int b = row_i >> 9;
    const size_t bbase = (size_t)b * NN;
    const int w = t >> 6, lane = t & 63;

    if (t < 9) rot_s[t] = rot[(size_t)row_i * 9 + t];
    if (t >= 9 && t < 12) trans_s[t - 9] = trans[(size_t)row_i * 3 + (t - 9)];

    // softmax (wave w handles heads w, w+4 of the local 6)
    for (int hh = w; hh < 6; hh += 4) {
        const float* lp = logits + ((size_t)row_i * NH + h0 + hh) * NN;
        float vreg[8];
        float m = -1e30f;
        #pragma unroll
        for (int s = 0; s < 8; ++s) { vreg[s] = lp[lane + 64 * s]; m = fmaxf(m, vreg[s]); }
        #pragma unroll
        for (int off = 32; off >= 1; off >>= 1) m = fmaxf(m, __shfl_xor(m, off, 64));
        float ssum = 0.f;
        #pragma unroll
        for (int s = 0; s < 8; ++s) { vreg[s] = __expf(vreg[s] - m); ssum += vreg[s]; }
        #pragma unroll
        for (int off = 32; off >= 1; off >>= 1) ssum += __shfl_xor(ssum, off, 64);
        float inv = 1.0f / ssum;
        #pragma unroll
        for (int s = 0; s < 8; ++s) attn6[hh][lane + 64 * s] = vreg[s] * inv;
    }
    __syncthreads();

    unsigned short* frow = featsb + (size_t)row_i * FEATD;

    // ---- vall phase: out_scalar (96) + rp_g (144) for 6 heads; 4-way j split
    {
        const int g4 = t & 63;
        const int jp = t >> 6;
        const bool active = (g4 < 60);
        const int c = 4 * g4;
        int arow = 0, vcol = 0;
        if (c < 96) { arow = c >> 4; vcol = h0 * 16 + c; }
        else        { int c2 = c - 96; arow = c2 / 24; vcol = 192 + h0 * 24 + c2; }
        float ax = 0.f, ay = 0.f, az = 0.f, aw = 0.f;
        if (active) {
            const float* vb = vall + bbase * VALLD + vcol;
            const float* ar = attn6[arow];
            for (int jj = 0; jj < 128; ++jj) {
                int j = 4 * jj + jp;
                float a = ar[j];
                float4 v4 = *(const float4*)(vb + (size_t)j * VALLD);
                ax += a * v4.x; ay += a * v4.y; az += a * v4.z; aw += a * v4.w;
            }
        }
        if (jp > 0 && active) {
            float4 st = {ax, ay, az, aw};
            *(float4*)&redbuf[jp * 256 + 4 * g4] = st;
        }
        __syncthreads();
        if (jp == 0 && active) {
            float4 r1 = *(const float4*)&redbuf[1 * 256 + 4 * g4];
            float4 r2 = *(const float4*)&redbuf[2 * 256 + 4 * g4];
            float4 r3 = *(const float4*)&redbuf[3 * 256 + 4 * g4];
            float o0 = ax + r1.x + r2.x + r3.x;
            float o1 = ay + r1.y + r2.y + r3.y;
            float o2 = az + r1.z + r2.z + r3.z;
            float o3 = aw + r1.w + r2.w + r3.w;
            if (c < 96) {
                ushort4 ov; ov.x = f2bf(o0); ov.y = f2bf(o1); ov.z = f2bf(o2); ov.w = f2bf(o3);
                *(ushort4*)(frow + h0 * 16 + c) = ov;
            } else {
                int c2 = c - 96;
                rp2_s[c2] = o0; rp2_s[c2 + 1] = o1; rp2_s[c2 + 2] = o2; rp2_s[c2 + 3] = o3;
            }
        }
        __syncthreads();
    }

    // ---- out_pair: 6 heads x 128 d; 8-way j split; cross-wave reduce in redbuf
    {
        const int g6 = t & 31;
        const int jp8 = t >> 5;
        float acc[6][4] = {{0.f}};
        const float* prow = pair + (size_t)row_i * NN * CZD + 4 * g6;
        for (int jj = 0; jj < 64; ++jj) {
            int j = 8 * jj + jp8;
            float4 p4 = *(const float4*)(prow + (size_t)j * CZD);
            #pragma unroll
            for (int hh = 0; hh < 6; ++hh) {
                float a = attn6[hh][j];
                acc[hh][0] += a * p4.x; acc[hh][1] += a * p4.y;
                acc[hh][2] += a * p4.z; acc[hh][3] += a * p4.w;
            }
        }
        #pragma unroll
        for (int hh = 0; hh < 6; ++hh)
            #pragma unroll
            for (int cc = 0; cc < 4; ++cc)
                acc[hh][cc] += __shfl_xor(acc[hh][cc], 32, 64);
        if (lane < 32) {
            float4* r2p = (float4*)redbuf;   // [4 waves][6 heads][32 g] = 768 float4
            #pragma unroll
            for (int hh = 0; hh < 6; ++hh) {
                float4 st = {acc[hh][0], acc[hh][1], acc[hh][2], acc[hh][3]};
                r2p[(w * 6 + hh) * 32 + g6] = st;
            }
        }
        __syncthreads();
        if (t < 192) {
            int hh = t >> 5, g = t & 31;
            const float4* r2p = (const float4*)redbuf;
            float4 s0 = r2p[(0 * 6 + hh) * 32 + g];
            float4 s1 = r2p[(1 * 6 + hh) * 32 + g];
            float4 s2 = r2p[(2 * 6 + hh) * 32 + g];
            float4 s3 = r2p[(3 * 6 + hh) * 32 + g];
            ushort4 ov;
            ov.x = f2bf(s0.x + s1.x + s2.x + s3.x);
            ov.y = f2bf(s0.y + s1.y + s2.y + s3.y);
            ov.z = f2bf(s0.z + s1.z + s2.z + s3.z);
            ov.w = f2bf(s0.w + s1.w + s2.w + s3.w);
            *(ushort4*)(frow + 576 + (size_t)(h0 + hh) * CZD + 4 * g) = ov;
        }
    }

    // ---- rp_l + norms for local 6 heads
    if (t < 48) {
        int h = t >> 3, p = t & 7;
        float d0 = rp2_s[h * 24 + p * 3 + 0] - trans_s[0];
        float d1 = rp2_s[h * 24 + p * 3 + 1] - trans_s[1];
        float d2v = rp2_s[h * 24 + p * 3 + 2] - trans_s[2];
        float l0 = rot_s[0] * d0 + rot_s[3] * d1 + rot_s[6] * d2v;
        float l1 = rot_s[1] * d0 + rot_s[4] * d1 + rot_s[7] * d2v;
        float l2 = rot_s[2] * d0 + rot_s[5] * d1 + rot_s[8] * d2v;
        float nrm = sqrtf(l0 * l0 + l1 * l1 + l2 * l2 + 1e-8f);
        int hp = (h0 + h) * 8 + p;
        frow[192 + hp] = f2bf(l0);
        frow[288 + hp] = f2bf(l1);
        frow[384 + hp] = f2bf(l2);
        frow[480 + hp] = f2bf(nrm);
    }
}

// ---------------- k_gemm2: out = feats_bf16 @ wo_bf16^T + bo ----------------
// M=1024, N=384, K=2112. grid (64, 6), 4 waves; wave = 16x16 tile.
__global__ __launch_bounds__(256) void k_gemm2(
    const unsigned short* __restrict__ A, const unsigned short* __restrict__ Bm,
    const float* __restrict__ bo, float* __restrict__ out)
{
    int w = threadIdx.x >> 6, lane = threadIdx.x & 63;
    int rt = blockIdx.x;
    int ct = blockIdx.y * 4 + w;
    int r = lane & 15, kq = lane >> 4;
    const unsigned short* ap = A  + (size_t)(rt * 16 + r) * FEATD + kq * 8;
    const unsigned short* bp = Bm + (size_t)(ct * 16 + r) * FEATD + kq * 8;
    f32x4 acc = {0.f, 0.f, 0.f, 0.f};
    #pragma unroll 2
    for (int ks = 0; ks < 66; ++ks) {
        short8 av = *(const short8*)(ap + ks * 32);
        short8 bv = *(const short8*)(bp + ks * 32);
        acc = __builtin_amdgcn_mfma_f32_16x16x32_bf16(av, bv, acc, 0, 0, 0);
    }
    int crow = rt * 16 + kq * 4;
    int ccol = ct * 16 + r;
    float bv = bo[ccol];
    #pragma unroll
    for (int i = 0; i < 4; ++i)
        out[(size_t)(crow + i) * CSD + ccol] = acc[i] + bv;
}

extern "C" void kernel_launch(void* const* d_in, const int* in_sizes, int n_in,
                              void* d_out, int out_size, void* d_ws, size_t ws_size,
                              hipStream_t stream) {
    const float* single = (const float*)d_in[0];
    const float* pair   = (const float*)d_in[1];
    const float* rot    = (const float*)d_in[2];
    const float* trans  = (const float*)d_in[3];
    const float* wq     = (const float*)d_in[4];
    const float* bq     = (const float*)d_in[5];
    const float* wkv    = (const float*)d_in[6];
    const float* bkv    = (const float*)d_in[7];
    const float* wqp    = (const float*)d_in[8];
    const float* bqp    = (const float*)d_in[9];
    const float* wkvp   = (const float*)d_in[10];
    const float* bkvp   = (const float*)d_in[11];
    const float* wb     = (const float*)d_in[12];
    const float* bb     = (const float*)d_in[13];
    const float* wo     = (const float*)d_in[14];
    const float* bo     = (const float*)d_in[15];
    const float* hw     = (const float*)d_in[16];
    float* out = (float*)d_out;

    float* ws = (float*)d_ws;
    // f32-slot layout (projraw aliases logits: disjoint lifetimes)
    float* logits  = ws;                      // 6,291,456 f32 (25 MB)
    float* projraw = ws;                      // 1,179,648 f32 (alias, consumed before logits written)
    float* vall    = ws + 6291456;            // 524,288
    float* qws     = vall + 524288;           // 196,608
    float* kws     = qws + 196608;            // 196,608
    float* qgws    = kws + 196608;            // 147,456
    float* kgws    = qgws + 147456;           // 147,456
    unsigned short* featsb  = (unsigned short*)(kgws + 147456);   // 2,162,688 bf16
    unsigned short* singleb = (unsigned short*)((float*)featsb + 1081344); // 393,216 bf16
    unsigned short* wallb   = (unsigned short*)((float*)singleb + 196608); // 442,368 bf16
    unsigned short* wob     = (unsigned short*)((float*)wallb + 221184);   // 811,008 bf16
    unsigned short* wbb     = wob + 811008;   // 2,048 bf16 (16x128 padded)
    // total ~9.41M f32 = 37.6 MB

    hipLaunchKernelGGL(k_cvt, dim3(1610), dim3(256), 0, stream,
                       single, wq, wkv, wqp, wkvp, wo, wb, singleb, wallb, wob, wbb);
    hipLaunchKernelGGL(k_gemm1, dim3(64, 18), dim3(256), 0, stream, singleb, wallb, projraw);
    hipLaunchKernelGGL(k_post, dim3(1024), dim3(256), 0, stream,
                       projraw, rot, trans, bq, bkv, bqp, bkvp, qws, kws, vall, qgws, kgws);
    hipLaunchKernelGGL(k_plog, dim3(4096), dim3(256), 0, stream,
                       pair, hw, wbb, bb, qws, kws, qgws, kgws, logits);
    hipLaunchKernelGGL(k_av, dim3(2048), dim3(256), 0, stream,
                       pair, rot, trans, logits, vall, featsb);
    hipLaunchKernelGGL(k_gemm2, dim3(64, 6), dim3(256), 0, stream, featsb, wob, bo, out);
}

// Round 7
// 191.886 us; speedup vs baseline: 3.3078x; 1.4947x over previous
//
#include <hip/hip_runtime.h>
#include <hip/hip_bf16.h>
#include <math.h>

#define NB 2
#define NN 512
#define CSD 384
#define CZD 128
#define NH 12
#define NC 16
#define NPQ 4
#define NPV 8
// derived
#define HC 192      // H*C
#define QPDIM 144   // 3*H*PQ
#define FEATD 2112  // H*C + H*PV*4 + H*CZ
#define VALLD 512   // padded 480 (192 scalar v + 288 vg)
#define WPT 0.13608276348795434f   // sqrt(1/(3*PQ*4.5))
#define RS3C 0.14433756729740643f  // sqrt(1/(3*C))
#define RS3 0.5773502691896258f    // sqrt(1/3)

typedef __attribute__((ext_vector_type(8))) short short8;
typedef __attribute__((ext_vector_type(4))) float f32x4;

static __device__ inline unsigned short f2bf(float x) {
    __hip_bfloat16 h = __float2bfloat16(x);
    return *reinterpret_cast<unsigned short*>(&h);
}
static __device__ inline unsigned short bflo(float x) {
    __hip_bfloat16 h = __float2bfloat16(x);
    return f2bf(x - __bfloat162float(h));
}

// ---------------- k_cvt: pack f32 -> bf16 (single, weights, wo, wb-padded) ----------------
#define R_S0 393216              // single
#define R_S1 (R_S0 + 73728)      // wq
#define R_S2 (R_S1 + 147456)     // wkv
#define R_S3 (R_S2 + 55296)      // wqp
#define R_S4 (R_S3 + 165888)     // wkvp
#define R_S5 (R_S4 + 811008)     // wo
#define R_S6 (R_S5 + 2048)       // wbb (16x128, rows 12..15 zero)
__global__ __launch_bounds__(256) void k_cvt(
    const float* __restrict__ single, const float* __restrict__ wq,
    const float* __restrict__ wkv, const float* __restrict__ wqp,
    const float* __restrict__ wkvp, const float* __restrict__ wo,
    const float* __restrict__ wb,
    unsigned short* __restrict__ singleb, unsigned short* __restrict__ wallb,
    unsigned short* __restrict__ wob, unsigned short* __restrict__ wbb)
{
    int gid = blockIdx.x * 256 + threadIdx.x;
    int e = gid * 4;
    if (e >= R_S6) return;
    if (e >= R_S5) {
        int c = e - R_S5;
        int hh = c >> 7;
        ushort4 o;
        if (hh < 12) {
            float4 v = *(const float4*)(wb + hh * 128 + (c & 127));
            o.x = f2bf(v.x); o.y = f2bf(v.y); o.z = f2bf(v.z); o.w = f2bf(v.w);
        } else { o.x = 0; o.y = 0; o.z = 0; o.w = 0; }
        *(ushort4*)(wbb + c) = o;
        return;
    }
    const float* src; unsigned short* dst;
    if (e < R_S0)      { src = single + e;          dst = singleb + e; }
    else if (e < R_S1) { src = wq + (e - R_S0);     dst = wallb + (e - R_S0); }
    else if (e < R_S2) { src = wkv + (e - R_S1);    dst = wallb + 73728 + (e - R_S1); }
    else if (e < R_S3) { src = wqp + (e - R_S2);    dst = wallb + 221184 + (e - R_S2); }
    else if (e < R_S4) { src = wkvp + (e - R_S3);   dst = wallb + 276480 + (e - R_S3); }
    else               { src = wo + (e - R_S4);     dst = wob + (e - R_S4); }
    float4 v = *(const float4*)src;
    ushort4 o;
    o.x = f2bf(v.x); o.y = f2bf(v.y); o.z = f2bf(v.z); o.w = f2bf(v.w);
    *(ushort4*)dst = o;
}

// ---------------- k_gemm1: projraw = single_bf16 @ wall_bf16^T ----------------
__global__ __launch_bounds__(256) void k_gemm1(
    const unsigned short* __restrict__ A, const unsigned short* __restrict__ Bm,
    float* __restrict__ Cr)
{
    int w = threadIdx.x >> 6, lane = threadIdx.x & 63;
    int rt = blockIdx.x;
    int ct = blockIdx.y * 4 + w;
    int r = lane & 15, kq = lane >> 4;
    const unsigned short* ap = A  + (size_t)(rt * 16 + r) * 384 + kq * 8;
    const unsigned short* bp = Bm + (size_t)(ct * 16 + r) * 384 + kq * 8;
    f32x4 acc = {0.f, 0.f, 0.f, 0.f};
    #pragma unroll 4
    for (int ks = 0; ks < 12; ++ks) {
        short8 av = *(const short8*)(ap + ks * 32);
        short8 bv = *(const short8*)(bp + ks * 32);
        acc = __builtin_amdgcn_mfma_f32_16x16x32_bf16(av, bv, acc, 0, 0, 0);
    }
    int crow = rt * 16 + kq * 4;
    int ccol = ct * 16 + r;
    #pragma unroll
    for (int i = 0; i < 4; ++i)
        Cr[(size_t)(crow + i) * 1152 + ccol] = acc[i];
}

// ---------------- k_post: biases + rotations + augmented MFMA operands ----------------
// grid 1024 (row = b*512+i), 256 thr
__global__ __launch_bounds__(256) void k_post(
    const float* __restrict__ praw, const float* __restrict__ rot, const float* __restrict__ trans,
    const float* __restrict__ hw,
    const float* __restrict__ bq, const float* __restrict__ bkv,
    const float* __restrict__ bqp, const float* __restrict__ bkvp,
    float* __restrict__ vall,
    unsigned short* __restrict__ qhat, unsigned short* __restrict__ khat,
    float* __restrict__ qn2, float* __restrict__ kn2)
{
    __shared__ float s_q[192], s_k[192], s_qp[QPDIM], s_kvp[432];
    __shared__ float s_qg[144], s_kg[144];
    __shared__ float s_sh[12];
    const int t = threadIdx.x;
    const int row = blockIdx.x;
    const int b = row >> 9;
    const int i = row & 511;

    if (t < 12) {
        float sp = log1pf(expf(hw[t]));
        s_sh[t] = RS3C / (WPT * sp);
    }
    const float* pr = praw + (size_t)row * 1152;
    for (int idx = t; idx < 1152; idx += 256) {
        float v = pr[idx];
        if (idx < 192) {
            s_q[idx] = v + bq[idx];
        } else if (idx < 576) {
            int f = idx - 192; float x = v + bkv[f];
            int h = f >> 5, cc = f & 31;
            if (cc < 16) s_k[h * 16 + cc] = x;
            else         vall[(size_t)row * VALLD + h * 16 + cc - 16] = x;
        } else if (idx < 720) {
            int f = idx - 576; s_qp[f] = v + bqp[f];
        } else {
            int f = idx - 720; s_kvp[f] = v + bkvp[f];
        }
    }
    __syncthreads();

    if (t < 192) {
        const float* R = rot + (size_t)row * 9;
        const float* T = trans + (size_t)row * 3;
        float lx, ly, lz; float* dst;
        if (t < 48) {
            lx = s_qp[t]; ly = s_qp[48 + t]; lz = s_qp[96 + t];
            dst = s_qg + t * 3;
        } else if (t < 96) {
            int idx = t - 48; int fb = (idx >> 2) * 12 + (idx & 3);
            lx = s_kvp[fb]; ly = s_kvp[144 + fb]; lz = s_kvp[288 + fb];
            dst = s_kg + idx * 3;
        } else {
            int idx = t - 96; int fb = (idx >> 3) * 12 + 4 + (idx & 7);
            lx = s_kvp[fb]; ly = s_kvp[144 + fb]; lz = s_kvp[288 + fb];
            dst = vall + (size_t)row * VALLD + 192 + idx * 3;
        }
        dst[0] = R[0] * lx + R[1] * ly + R[2] * lz + T[0];
        dst[1] = R[3] * lx + R[4] * ly + R[5] * lz + T[1];
        dst[2] = R[6] * lx + R[7] * ly + R[8] * lz + T[2];
    }
    __syncthreads();

    // norms
    if (t < 24) {
        int h = t % 12;
        const float* g = (t < 12) ? (s_qg + h * 12) : (s_kg + h * 12);
        float s = 0.f;
        #pragma unroll
        for (int e = 0; e < 12; ++e) s += g[e] * g[e];
        float* dst = (t < 12) ? qn2 : kn2;
        dst[((size_t)b * 12 + h) * 512 + i] = s;
    }

    // augmented vectors: qhat [sh*q(16), qg_hi(12), qg_hi(12), qg_lo(12), 0(12)]
    //                    khat [k(16),    kg_hi(12), kg_lo(12), kg_hi(12), 0(12)]
    for (int idx = t; idx < 768; idx += 256) {
        int side = idx >= 384;
        int li = side ? (idx - 384) : idx;   // FIX: was idx & 383 (383 != 2^n-1)
        int h = li >> 5, s2 = li & 31;
        unsigned short o[2];
        #pragma unroll
        for (int u = 0; u < 2; ++u) {
            int k = 2 * s2 + u;
            unsigned short val = 0;
            if (!side) {
                if (k < 16)      val = f2bf(s_sh[h] * s_q[h * 16 + k]);
                else if (k < 28) val = f2bf(s_qg[h * 12 + k - 16]);
                else if (k < 40) val = f2bf(s_qg[h * 12 + k - 28]);
                else if (k < 52) val = bflo(s_qg[h * 12 + k - 40]);
            } else {
                if (k < 16)      val = f2bf(s_k[h * 16 + k]);
                else if (k < 28) val = f2bf(s_kg[h * 12 + k - 16]);
                else if (k < 40) val = bflo(s_kg[h * 12 + k - 28]);
                else if (k < 52) val = f2bf(s_kg[h * 12 + k - 40]);
            }
            o[u] = val;
        }
        unsigned short* dst = (side ? khat : qhat) + (((size_t)b * 12 + h) * 512 + i) * 64 + 2 * s2;
        *(ushort2*)dst = make_ushort2(o[0], o[1]);
    }
}

// ---------------- k_qk: plog = m*MFMA(qhat,khat) + coef*(qn2+kn2) ----------------
// grid (24, 64): bh, 8x8 tiles of 64x64. 256 thr.
__global__ __launch_bounds__(256) void k_qk(
    const unsigned short* __restrict__ qhat, const unsigned short* __restrict__ khat,
    const float* __restrict__ qn2, const float* __restrict__ kn2,
    const float* __restrict__ hw, float* __restrict__ plog)
{
    int w = threadIdx.x >> 6, lane = threadIdx.x & 63;
    int bh = blockIdx.x;
    int i0 = (blockIdx.y >> 3) * 64;
    int j0 = (blockIdx.y & 7) * 64;
    int r = lane & 15, kq = lane >> 4;
    float sp = log1pf(expf(hw[bh % 12]));
    float m = WPT * sp;
    float coef = -0.5f * m;

    const unsigned short* ap = qhat + ((size_t)bh * 512 + i0 + w * 16 + r) * 64 + kq * 8;
    short8 a0 = *(const short8*)(ap);
    short8 a1 = *(const short8*)(ap + 32);
    const unsigned short* bpb = khat + ((size_t)bh * 512 + j0 + r) * 64 + kq * 8;
    f32x4 acc[4];
    #pragma unroll
    for (int jt = 0; jt < 4; ++jt) {
        short8 b0 = *(const short8*)(bpb + (size_t)jt * 1024);
        short8 b1 = *(const short8*)(bpb + (size_t)jt * 1024 + 32);
        f32x4 a = {0.f, 0.f, 0.f, 0.f};
        a = __builtin_amdgcn_mfma_f32_16x16x32_bf16(a0, b0, a, 0, 0, 0);
        a = __builtin_amdgcn_mfma_f32_16x16x32_bf16(a1, b1, a, 0, 0, 0);
        acc[jt] = a;
    }
    int crow = i0 + w * 16 + kq * 4;
    const float* qn = qn2 + (size_t)bh * 512;
    const float* kn = kn2 + (size_t)bh * 512;
    #pragma unroll
    for (int jt = 0; jt < 4; ++jt) {
        int ccol = j0 + jt * 16 + r;
        float knv = kn[ccol];
        #pragma unroll
        for (int ii = 0; ii < 4; ++ii)
            plog[((size_t)bh * 512 + crow + ii) * 512 + ccol] =
                m * acc[jt][ii] + coef * (qn[crow + ii] + knv);
    }
}

// ---------------- k_av: bias MFMA + plog + softmax + AV + out_pair + rp_l ----------------
// grid 1024 (row_i), 512 thr
__global__ __launch_bounds__(512) void k_av(
    const float* __restrict__ pair, const float* __restrict__ rot, const float* __restrict__ trans,
    const unsigned short* __restrict__ wbb, const float* __restrict__ bb,
    const float* __restrict__ plog, const float* __restrict__ vall,
    unsigned short* __restrict__ featsb)
{
    __shared__ float attn12[12][521];
    __shared__ float rp2_s[288];
    __shared__ float redv[3][480];
    __shared__ float rot_s[9], trans_s[3];

    const int t = threadIdx.x;
    const int row_i = blockIdx.x;
    const int b = row_i >> 9;
    const size_t bbase = (size_t)b * NN;
    const int w = t >> 6, lane = t & 63;
    const int r = lane & 15, kq = lane >> 4;

    if (t < 9) rot_s[t] = rot[(size_t)row_i * 9 + t];
    if (t >= 9 && t < 12) trans_s[t - 9] = trans[(size_t)row_i * 3 + (t - 9)];

    // ---- Phase 0a: bias via MFMA (8 waves x 4 tiles of 16 j-rows)
    {
        const unsigned short* bp = wbb + r * 128 + kq * 8;
        short8 bfrag[4];
        #pragma unroll
        for (int ks = 0; ks < 4; ++ks) bfrag[ks] = *(const short8*)(bp + ks * 32);
        float bbv = (r < 12) ? bb[r] : 0.f;
        #pragma unroll
        for (int tt = 0; tt < 4; ++tt) {
            int tile = w + tt * 8;
            const float* ap = pair + ((size_t)row_i * NN + tile * 16 + r) * CZD + kq * 8;
            float4 p[8];
            #pragma unroll
            for (int ks = 0; ks < 4; ++ks) {
                p[2 * ks]     = *(const float4*)(ap + ks * 32);
                p[2 * ks + 1] = *(const float4*)(ap + ks * 32 + 4);
            }
            f32x4 acc = {0.f, 0.f, 0.f, 0.f};
            #pragma unroll
            for (int ks = 0; ks < 4; ++ks) {
                short8 av;
                av[0] = (short)f2bf(p[2*ks].x);   av[1] = (short)f2bf(p[2*ks].y);
                av[2] = (short)f2bf(p[2*ks].z);   av[3] = (short)f2bf(p[2*ks].w);
                av[4] = (short)f2bf(p[2*ks+1].x); av[5] = (short)f2bf(p[2*ks+1].y);
                av[6] = (short)f2bf(p[2*ks+1].z); av[7] = (short)f2bf(p[2*ks+1].w);
                acc = __builtin_amdgcn_mfma_f32_16x16x32_bf16(av, bfrag[ks], acc, 0, 0, 0);
            }
            if (r < 12) {
                #pragma unroll
                for (int ii = 0; ii < 4; ++ii)
                    attn12[r][tile * 16 + kq * 4 + ii] = RS3 * (acc[ii] + bbv);
            }
        }
    }
    __syncthreads();

    // ---- Phase 0b: += plog
    #pragma unroll
    for (int it = 0; it < 3; ++it) {
        int idx4 = it * 512 + t;          // 1536 float4 tasks
        int h = idx4 >> 7;
        int j4 = (idx4 & 127) * 4;
        const float* lp = plog + (((size_t)b * 12 + h) * 512 + (row_i & 511)) * 512 + j4;
        float4 lv = *(const float4*)lp;
        attn12[h][j4 + 0] += lv.x;
        attn12[h][j4 + 1] += lv.y;
        attn12[h][j4 + 2] += lv.z;
        attn12[h][j4 + 3] += lv.w;
    }
    __syncthreads();

    // ---- softmax: wave w -> heads w, w+8
    for (int hh = w; hh < 12; hh += 8) {
        float vreg[8];
        float mx = -1e30f;
        #pragma unroll
        for (int s = 0; s < 8; ++s) { vreg[s] = attn12[hh][lane + 64 * s]; mx = fmaxf(mx, vreg[s]); }
        #pragma unroll
        for (int off = 32; off >= 1; off >>= 1) mx = fmaxf(mx, __shfl_xor(mx, off, 64));
        float ssum = 0.f;
        #pragma unroll
        for (int s = 0; s < 8; ++s) { vreg[s] = __expf(vreg[s] - mx); ssum += vreg[s]; }
        #pragma unroll
        for (int off = 32; off >= 1; off >>= 1) ssum += __shfl_xor(ssum, off, 64);
        float inv = 1.0f / ssum;
        #pragma unroll
        for (int s = 0; s < 8; ++s) attn12[hh][lane + 64 * s] = vreg[s] * inv;
    }
    __syncthreads();

    unsigned short* frow = featsb + (size_t)row_i * FEATD;

    // ---- out_pair: wave w owns d-range [w*16, w*16+16); lanes: jp=lane>>2 (16-way j), dg=lane&3
    {
        const int jp = lane >> 2;
        const int dg = lane & 3;
        const int d0 = w * 16 + dg * 4;
        float4 acc12[12];
        #pragma unroll
        for (int hh = 0; hh < 12; ++hh) acc12[hh] = make_float4(0.f, 0.f, 0.f, 0.f);
        const float* pb = pair + (size_t)row_i * NN * CZD + d0;
        for (int jj = 0; jj < 32; ++jj) {
            int j = jj * 16 + jp;
            float4 p4 = *(const float4*)(pb + (size_t)j * CZD);
            #pragma unroll
            for (int hh = 0; hh < 12; ++hh) {
                float a = attn12[hh][j];
                acc12[hh].x += a * p4.x; acc12[hh].y += a * p4.y;
                acc12[hh].z += a * p4.z; acc12[hh].w += a * p4.w;
            }
        }
        #pragma unroll
        for (int off = 4; off <= 32; off <<= 1) {
            #pragma unroll
            for (int hh = 0; hh < 12; ++hh) {
                acc12[hh].x += __shfl_xor(acc12[hh].x, off, 64);
                acc12[hh].y += __shfl_xor(acc12[hh].y, off, 64);
                acc12[hh].z += __shfl_xor(acc12[hh].z, off, 64);
                acc12[hh].w += __shfl_xor(acc12[hh].w, off, 64);
            }
        }
        if (jp == 0) {
            #pragma unroll
            for (int hh = 0; hh < 12; ++hh) {
                ushort4 ov;
                ov.x = f2bf(acc12[hh].x); ov.y = f2bf(acc12[hh].y);
                ov.z = f2bf(acc12[hh].z); ov.w = f2bf(acc12[hh].w);
                *(ushort4*)(frow + 576 + hh * CZD + d0) = ov;
            }
        }
    }

    // ---- vall phase: out_scalar (192) + rp_g (288); 4-way j split
    {
        const int g4 = t & 127;
        const int jp = t >> 7;
        const bool active = (g4 < 120);
        const int c = 4 * g4;
        int arow = 0;
        if (active) arow = (c < 192) ? (c >> 4) : ((c - 192) / 24);
        float ax = 0.f, ay = 0.f, az = 0.f, aw = 0.f;
        if (active) {
            const float* vb = vall + bbase * VALLD + c;
            const float* ar = attn12[arow];
            for (int jj = 0; jj < 128; ++jj) {
                int j = 4 * jj + jp;
                float a = ar[j];
                float4 v4 = *(const float4*)(vb + (size_t)j * VALLD);
                ax += a * v4.x; ay += a * v4.y; az += a * v4.z; aw += a * v4.w;
            }
        }
        if (jp > 0 && active) {
            float4 st = {ax, ay, az, aw};
            *(float4*)&redv[jp - 1][c] = st;
        }
        __syncthreads();
        if (jp == 0 && active) {
            float4 r1 = *(const float4*)&redv[0][c];
            float4 r2 = *(const float4*)&redv[1][c];
            float4 r3 = *(const float4*)&redv[2][c];
            float o0 = ax + r1.x + r2.x + r3.x;
            float o1 = ay + r1.y + r2.y + r3.y;
            float o2 = az + r1.z + r2.z + r3.z;
            float o3 = aw + r1.w + r2.w + r3.w;
            if (c < 192) {
                ushort4 ov; ov.x = f2bf(o0); ov.y = f2bf(o1); ov.z = f2bf(o2); ov.w = f2bf(o3);
                *(ushort4*)(frow + c) = ov;
            } else {
                rp2_s[c - 192] = o0; rp2_s[c - 191] = o1;
                rp2_s[c - 190] = o2; rp2_s[c - 189] = o3;
            }
        }
    }
    __syncthreads();

    // ---- rp_l + norms
    if (t < 96) {
        int h = t >> 3, p = t & 7;
        float d0 = rp2_s[h * 24 + p * 3 + 0] - trans_s[0];
        float d1 = rp2_s[h * 24 + p * 3 + 1] - trans_s[1];
        float d2v = rp2_s[h * 24 + p * 3 + 2] - trans_s[2];
        float l0 = rot_s[0] * d0 + rot_s[3] * d1 + rot_s[6] * d2v;
        float l1 = rot_s[1] * d0 + rot_s[4] * d1 + rot_s[7] * d2v;
        float l2 = rot_s[2] * d0 + rot_s[5] * d1 + rot_s[8] * d2v;
        float nrm = sqrtf(l0 * l0 + l1 * l1 + l2 * l2 + 1e-8f);
        int hp = h * 8 + p;
        frow[192 + hp] = f2bf(l0);
        frow[288 + hp] = f2bf(l1);
        frow[384 + hp] = f2bf(l2);
        frow[480 + hp] = f2bf(nrm);
    }
}

// ---------------- k_gemm2: out = feats_bf16 @ wo_bf16^T + bo ----------------
__global__ __launch_bounds__(256) void k_gemm2(
    const unsigned short* __restrict__ A, const unsigned short* __restrict__ Bm,
    const float* __restrict__ bo, float* __restrict__ out)
{
    int w = threadIdx.x >> 6, lane = threadIdx.x & 63;
    int rt = blockIdx.x;
    int ct = blockIdx.y * 4 + w;
    int r = lane & 15, kq = lane >> 4;
    const unsigned short* ap = A  + (size_t)(rt * 16 + r) * FEATD + kq * 8;
    const unsigned short* bp = Bm + (size_t)(ct * 16 + r) * FEATD + kq * 8;
    f32x4 acc = {0.f, 0.f, 0.f, 0.f};
    #pragma unroll 2
    for (int ks = 0; ks < 66; ++ks) {
        short8 av = *(const short8*)(ap + ks * 32);
        short8 bv = *(const short8*)(bp + ks * 32);
        acc = __builtin_amdgcn_mfma_f32_16x16x32_bf16(av, bv, acc, 0, 0, 0);
    }
    int crow = rt * 16 + kq * 4;
    int ccol = ct * 16 + r;
    float bv = bo[ccol];
    #pragma unroll
    for (int i = 0; i < 4; ++i)
        out[(size_t)(crow + i) * CSD + ccol] = acc[i] + bv;
}

extern "C" void kernel_launch(void* const* d_in, const int* in_sizes, int n_in,
                              void* d_out, int out_size, void* d_ws, size_t ws_size,
                              hipStream_t stream) {
    const float* single = (const float*)d_in[0];
    const float* pair   = (const float*)d_in[1];
    const float* rot    = (const float*)d_in[2];
    const float* trans  = (const float*)d_in[3];
    const float* wq     = (const float*)d_in[4];
    const float* bq     = (const float*)d_in[5];
    const float* wkv    = (const float*)d_in[6];
    const float* bkv    = (const float*)d_in[7];
    const float* wqp    = (const float*)d_in[8];
    const float* bqp    = (const float*)d_in[9];
    const float* wkvp   = (const float*)d_in[10];
    const float* bkvp   = (const float*)d_in[11];
    const float* wb     = (const float*)d_in[12];
    const float* bb     = (const float*)d_in[13];
    const float* wo     = (const float*)d_in[14];
    const float* bo     = (const float*)d_in[15];
    const float* hw     = (const float*)d_in[16];
    float* out = (float*)d_out;

    float* ws = (float*)d_ws;
    // layout (f32 slots); projraw aliases plog (disjoint lifetimes)
    float* plog    = ws;                      // 6,291,456
    float* projraw = ws;                      // 1,179,648 (alias)
    float* vall    = ws + 6291456;            // 524,288
    unsigned short* qhat = (unsigned short*)(vall + 524288);   // 786,432 bf16 (393,216 slots)
    unsigned short* khat = (unsigned short*)((float*)qhat + 393216); // 786,432 bf16
    float* qn2     = (float*)khat + 393216;   // 12,288
    float* kn2     = qn2 + 12288;             // 12,288
    unsigned short* featsb  = (unsigned short*)(kn2 + 12288);  // 2,162,688 bf16 (1,081,344 slots)
    unsigned short* singleb = (unsigned short*)((float*)featsb + 1081344); // 393,216 bf16
    unsigned short* wallb   = (unsigned short*)((float*)singleb + 196608); // 442,368 bf16
    unsigned short* wob     = (unsigned short*)((float*)wallb + 221184);   // 811,008 bf16
    unsigned short* wbb     = wob + 811008;   // 2,048 bf16
    // total ~9.53M f32 = 38.1 MB

    hipLaunchKernelGGL(k_cvt, dim3(1610), dim3(256), 0, stream,
                       single, wq, wkv, wqp, wkvp, wo, wb, singleb, wallb, wob, wbb);
    hipLaunchKernelGGL(k_gemm1, dim3(64, 18), dim3(256), 0, stream, singleb, wallb, projraw);
    hipLaunchKernelGGL(k_post, dim3(1024), dim3(256), 0, stream,
                       projraw, rot, trans, hw, bq, bkv, bqp, bkvp,
                       vall, qhat, khat, qn2, kn2);
    hipLaunchKernelGGL(k_qk, dim3(24, 64), dim3(256), 0, stream,
                       qhat, khat, qn2, kn2, hw, plog);
    hipLaunchKernelGGL(k_av, dim3(1024), dim3(512), 0, stream,
                       pair, rot, trans, wbb, bb, plog, vall, featsb);
    hipLaunchKernelGGL(k_gemm2, dim3(64, 6), dim3(256), 0, stream, featsb, wob, bo, out);
}